// Round 5
// baseline (25215.302 us; speedup 1.0000x reference)
//
#include <hip/hip_runtime.h>
#include <math.h>

#define N_NODES 100000
#define N_GRAPHS 100
#define N_EDGES 1000000
#define H 256
#define L_POS 512
#define CH_T 25000    // transform src-chunk (4 chunks)
#define CH_G 5000     // GRU row-chunk (20 chunks)

typedef short bf16x8 __attribute__((ext_vector_type(8)));
typedef float f32x4  __attribute__((ext_vector_type(4)));

__device__ inline short f2bf(float f) {
    union { float f; unsigned u; } v; v.f = f;
    unsigned r = (v.u + 0x7FFF + ((v.u >> 16) & 1)) >> 16;
    return (short)r;
}
__device__ inline float bf2f(unsigned short u) {
    union { unsigned u; float f; } v; v.u = ((unsigned)u) << 16;
    return v.f;
}

// ---------------- zero fill (float4) ----------------
__global__ void zero_kernel(float4* __restrict__ p, int n4)
{
    int i = blockIdx.x * 256 + threadIdx.x;
    if (i < n4) p[i] = make_float4(0.f, 0.f, 0.f, 0.f);
}

__global__ void zero_meta(int* __restrict__ p, int n)
{
    int i = threadIdx.x;
    if (i < n) p[i] = 0;
}

// ---------------- init h: h = embed[tok] + pe[min(pos,512)] ----------------
__global__ void init_h_kernel(const int* __restrict__ nodes,
                              const float* __restrict__ embed,
                              float* __restrict__ h)
{
    int n = blockIdx.x;
    int j = threadIdx.x;
    int tok = nodes[n];
    int p = nodes[N_NODES + n];
    if (p > L_POS) p = L_POS;
    float pe = 0.0f;
    if (p > 0) {
        float pos = (float)(p - 1);
        float denom = powf(10000.0f, 2.0f * (float)j / (float)H);
        float ang = pos / denom;
        pe = (j & 1) ? cosf(ang) : sinf(ang);
    }
    h[(size_t)n * H + j] = embed[(size_t)tok * H + j] + pe;
}

// ---------------- weight convert+transpose kernels ----------------
// typeWT[m][n][k] = type_w[m][k][n], m in [0,8)
__global__ void cvt_typew(const float* __restrict__ w, short* __restrict__ wt)
{
    int idx = blockIdx.x * 256 + threadIdx.x;
    if (idx >= 8 * 256 * 256) return;
    int m = idx >> 16;
    int n = (idx >> 8) & 255;
    int k = idx & 255;
    wt[idx] = f2bf(w[((size_t)m * 256 + k) * 256 + n]);
}
// gWT[l][n][k] = gw[l][k][n], n in [0,768)
__global__ void cvt_gruw(const float* __restrict__ gw, short* __restrict__ gwt)
{
    int idx = blockIdx.x * 256 + threadIdx.x;
    if (idx >= 2 * 768 * 256) return;
    int l = idx / (768 * 256);
    int rem = idx % (768 * 256);
    int n = rem >> 8;
    int k = rem & 255;
    gwt[idx] = f2bf(gw[((size_t)l * 256 + k) * 768 + n]);
}

// ---------------- edge bucketing: bucket = (src/CH_T)*4 + etype ----------------
__global__ void histo_kernel(const int* __restrict__ edges, int* __restrict__ counts)
{
    __shared__ int lc[16];
    if (threadIdx.x < 16) lc[threadIdx.x] = 0;
    __syncthreads();
    int e = blockIdx.x * 256 + threadIdx.x;
    if (e < N_EDGES) {
        int t = edges[e * 3];
        int s = edges[e * 3 + 1];
        atomicAdd(&lc[(s / CH_T) * 4 + t], 1);
    }
    __syncthreads();
    if (threadIdx.x < 16 && lc[threadIdx.x]) atomicAdd(&counts[threadIdx.x], lc[threadIdx.x]);
}

__global__ void scan_kernel(const int* __restrict__ counts, int* __restrict__ offs)
{
    if (blockIdx.x == 0 && threadIdx.x == 0) {
        int acc = 0;
        for (int i = 0; i < 16; i++) { offs[i] = acc; acc += counts[i]; }
        offs[16] = acc;
    }
}

__global__ void fill_kernel(const int* __restrict__ edges, const int* __restrict__ offs,
                            int* __restrict__ cursors, int2* __restrict__ list)
{
    int e = blockIdx.x * 256 + threadIdx.x;
    if (e >= N_EDGES) return;
    int t = edges[e * 3];
    int s = edges[e * 3 + 1];
    int tg = edges[e * 3 + 2];
    int b = (s / CH_T) * 4 + t;
    int p = atomicAdd(&cursors[b], 1);
    list[offs[b] + p] = make_int2(s, tg);
}

// ---- bf16 MFMA matmul: C(nrows x gridDim.y*128) = bf16(A fp32, nrows x 256) @ BT^T + bias [+C]
// BT is bf16, transposed: BT[col][k], k in [0,256). C fp32 (ldc) or bf16 (c_bf16).
__global__ __launch_bounds__(256) void mm_bf16(
    const float* __restrict__ A, const short* __restrict__ BT,
    const float* __restrict__ bias, void* __restrict__ Cv,
    int nrows, int ldc, int accumulate, int c_bf16)
{
    __shared__ short As[128 * 40];   // [row][k], stride 40 (80B: 16B-aligned, 2-way-free banks)
    __shared__ short Bs[128 * 40];   // [col][k]
    const int tid = threadIdx.x;
    const int bm = blockIdx.x * 128;
    const int bn = blockIdx.y * 128;
    const int lane = tid & 63;
    const int wave = tid >> 6;
    const int wm = (wave >> 1) * 64;
    const int wn = (wave & 1) * 64;
    const int q = lane >> 4;
    const int r16 = lane & 15;

    f32x4 acc[4][4];
    #pragma unroll
    for (int i = 0; i < 4; i++)
        #pragma unroll
        for (int j = 0; j < 4; j++)
            acc[i][j] = (f32x4){0.f, 0.f, 0.f, 0.f};

    const int srow = tid >> 1;         // 0..127
    const int skh  = (tid & 1) * 16;   // 0 or 16
    const int agr  = bm + srow;
    const bool aok = agr < nrows;
    const float* Ap = A + (size_t)agr * 256 + skh;
    const short* Bp = BT + (size_t)(bn + srow) * 256 + skh;

    for (int k0 = 0; k0 < 256; k0 += 32) {
        short tmp[16];
        if (aok) {
            #pragma unroll
            for (int i = 0; i < 4; i++) {
                float4 v = *(const float4*)(Ap + k0 + i * 4);
                tmp[i*4+0] = f2bf(v.x); tmp[i*4+1] = f2bf(v.y);
                tmp[i*4+2] = f2bf(v.z); tmp[i*4+3] = f2bf(v.w);
            }
        } else {
            #pragma unroll
            for (int i = 0; i < 16; i++) tmp[i] = 0;
        }
        uint4 b0 = *(const uint4*)(Bp + k0);
        uint4 b1 = *(const uint4*)(Bp + k0 + 8);

        __syncthreads();
        *(bf16x8*)&As[srow * 40 + skh]     = *(bf16x8*)&tmp[0];
        *(bf16x8*)&As[srow * 40 + skh + 8] = *(bf16x8*)&tmp[8];
        *(uint4*)&Bs[srow * 40 + skh]      = b0;
        *(uint4*)&Bs[srow * 40 + skh + 8]  = b1;
        __syncthreads();

        bf16x8 af[4], bfr[4];
        #pragma unroll
        for (int mt = 0; mt < 4; mt++)
            af[mt] = *(const bf16x8*)&As[(wm + mt * 16 + r16) * 40 + q * 8];
        #pragma unroll
        for (int nt = 0; nt < 4; nt++)
            bfr[nt] = *(const bf16x8*)&Bs[(wn + nt * 16 + r16) * 40 + q * 8];
        #pragma unroll
        for (int mt = 0; mt < 4; mt++)
            #pragma unroll
            for (int nt = 0; nt < 4; nt++)
                acc[mt][nt] = __builtin_amdgcn_mfma_f32_16x16x32_bf16(af[mt], bfr[nt], acc[mt][nt], 0, 0, 0);
    }

    // epilogue: D[row=q*4+reg][col=r16] per 16x16 tile
    #pragma unroll
    for (int mt = 0; mt < 4; mt++) {
        #pragma unroll
        for (int reg = 0; reg < 4; reg++) {
            int row = bm + wm + mt * 16 + q * 4 + reg;
            if (row >= nrows) continue;
            #pragma unroll
            for (int nt = 0; nt < 4; nt++) {
                int col = bn + wn + nt * 16 + r16;
                float v = acc[mt][nt][reg] + bias[col];
                if (c_bf16) {
                    ((short*)Cv)[(size_t)row * ldc + col] = f2bf(v);
                } else {
                    float* C = (float*)Cv;
                    if (accumulate) v += C[(size_t)row * ldc + col];
                    C[(size_t)row * ldc + col] = v;
                }
            }
        }
    }
}

// ---- bucketed scatter: msgs[tgt] += fp32(transCh[src-c0]), grid-stride over bucket ----
__global__ __launch_bounds__(256) void scatter_kernel(const int2* __restrict__ list,
                                                      const int* __restrict__ offs,
                                                      int bucket, int c0,
                                                      const short* __restrict__ transCh,
                                                      float* __restrict__ msgs)
{
    int off = offs[bucket];
    int cnt = offs[bucket + 1] - off;
    int w = (blockIdx.x * 256 + threadIdx.x) >> 6;
    int lane = threadIdx.x & 63;
    int nw = (gridDim.x * 256) >> 6;
    for (int e = w; e < cnt; e += nw) {
        int2 st = list[off + e];
        const short* trow = transCh + (size_t)(st.x - c0) * H + lane * 4;
        uint2 pk = *(const uint2*)trow;
        float* dst = msgs + (size_t)st.y * H + lane * 4;
        unsafeAtomicAdd(dst + 0, bf2f((unsigned short)(pk.x & 0xFFFF)));
        unsafeAtomicAdd(dst + 1, bf2f((unsigned short)(pk.x >> 16)));
        unsafeAtomicAdd(dst + 2, bf2f((unsigned short)(pk.y & 0xFFFF)));
        unsafeAtomicAdd(dst + 3, bf2f((unsigned short)(pk.y >> 16)));
    }
}

// ---- GRU elementwise for a row chunk. Sch rows: [z|r|xh] (768); HHch rows: hh (256). h in place.
__global__ void gru_kernel(float* __restrict__ h, const float* __restrict__ S,
                           const float* __restrict__ HH, int r0, int nrows)
{
    int nl = blockIdx.x;
    if (nl >= nrows) return;
    int j = threadIdx.x;
    int n = r0 + nl;
    const float* Srow = S + (size_t)nl * 768;
    float sz = Srow[j];
    float sr = Srow[256 + j];
    float xh = Srow[512 + j];
    float hh = HH[(size_t)nl * 256 + j];
    size_t idx = (size_t)n * 256 + j;
    float hv = h[idx];
    float z = 1.0f / (1.0f + expf(-sz));
    float r = 1.0f / (1.0f + expf(-sr));
    float cand = tanhf(xh + r * hh);
    h[idx] = z * hv + (1.0f - z) * cand;
}

// ---------------- gate logits: g[n] = h[n] . gate_W + gate_b (wave per node) ----------------
__global__ __launch_bounds__(256) void gate_kernel(const float* __restrict__ h,
                                                   const float* __restrict__ gW,
                                                   const float* __restrict__ gb,
                                                   float* __restrict__ g)
{
    int tid = blockIdx.x * 256 + threadIdx.x;
    int n = tid >> 6;
    if (n >= N_NODES) return;
    int lane = tid & 63;
    float s = 0.0f;
    #pragma unroll
    for (int j = 0; j < 4; j++)
        s += h[(size_t)n * H + lane + j * 64] * gW[lane + j * 64];
    #pragma unroll
    for (int off = 32; off > 0; off >>= 1)
        s += __shfl_down(s, off);
    if (lane == 0) g[n] = s + gb[0];
}

// ---------------- per-graph softmax-gated readout (block per graph) ----------------
__global__ __launch_bounds__(256) void out_kernel(const float* __restrict__ h,
                                                  const float* __restrict__ g,
                                                  const int* __restrict__ sizes,
                                                  const float* __restrict__ outW,
                                                  const float* __restrict__ outB,
                                                  float* __restrict__ out)
{
    __shared__ float red[256];
    int gid = blockIdx.x;
    int tid = threadIdx.x;

    int start = 0, end = 0;
    {
        int c = 0;
        for (int i = 0; i < N_GRAPHS; i++) {
            int sz = sizes[i];
            if (i == gid) { start = c; end = c + sz; }
            c += sz;
        }
    }

    float m = -INFINITY;
    for (int n = start + tid; n < end; n += 256) m = fmaxf(m, g[n]);
    red[tid] = m; __syncthreads();
    for (int s = 128; s > 0; s >>= 1) {
        if (tid < s) red[tid] = fmaxf(red[tid], red[tid + s]);
        __syncthreads();
    }
    m = red[0]; __syncthreads();

    float s_ = 0.0f;
    for (int n = start + tid; n < end; n += 256) s_ += expf(g[n] - m);
    red[tid] = s_; __syncthreads();
    for (int s = 128; s > 0; s >>= 1) {
        if (tid < s) red[tid] += red[tid + s];
        __syncthreads();
    }
    float ssum = red[0]; __syncthreads();

    float acc = 0.0f;
    for (int n = start; n < end; n++) {
        float e = expf(g[n] - m);
        acc += e * h[(size_t)n * H + tid];
    }

    float inv = 1.0f / (ssum + 1e-16f);
    for (int c = 0; c < 2; c++) {
        red[tid] = acc * outW[tid * 2 + c];
        __syncthreads();
        for (int s = 128; s > 0; s >>= 1) {
            if (tid < s) red[tid] += red[tid + s];
            __syncthreads();
        }
        if (tid == 0) out[gid * 2 + c] = red[0] * inv + outB[c] * (ssum * inv);
        __syncthreads();
    }
}

extern "C" void kernel_launch(void* const* d_in, const int* in_sizes, int n_in,
                              void* d_out, int out_size, void* d_ws, size_t ws_size,
                              hipStream_t stream)
{
    const int*   nodes  = (const int*)d_in[0];
    const int*   gsizes = (const int*)d_in[1];
    const int*   edges  = (const int*)d_in[2];
    const float* embed  = (const float*)d_in[3];
    const float* type_w = (const float*)d_in[4];
    const float* type_b = (const float*)d_in[5];
    const float* gru_W  = (const float*)d_in[6];
    const float* gru_U  = (const float*)d_in[7];
    const float* gru_bi = (const float*)d_in[8];
    const float* gru_br = (const float*)d_in[9];
    const float* gate_W = (const float*)d_in[10];
    const float* gate_b = (const float*)d_in[11];
    const float* out_W  = (const float*)d_in[12];
    const float* out_b  = (const float*)d_in[13];
    float* out = (float*)d_out;

    // ---- workspace layout (bytes) ----
    const size_t SZ_H    = (size_t)N_NODES * H * 4;                 // 102.4 MB
    const size_t SZ_MSG  = SZ_H;                                     // 102.4 MB
    const size_t SZ_SCR  = (size_t)CH_G * 1024 * 4;                  // 20.48 MB (>= 12.8 MB trans chunk)
    const size_t SZ_G    = (size_t)N_NODES * 4;
    const size_t SZ_TWT  = (size_t)8 * 256 * 256 * 2;                // 1.05 MB
    const size_t SZ_GWT  = (size_t)2 * 768 * 256 * 2;                // 0.79 MB
    const size_t SZ_LIST = (size_t)N_EDGES * 8;                      // 8 MB
    const size_t SZ_META = 256;
    size_t need = SZ_H + SZ_MSG + SZ_SCR + SZ_G + SZ_TWT + 2 * SZ_GWT + SZ_LIST + SZ_META;
    if (ws_size < need) return;   // clean fail (absmax ~= 0.586), not a crash

    char* base = (char*)d_ws;
    float* h      = (float*)base;                 base += SZ_H;
    float* msgs   = (float*)base;                 base += SZ_MSG;
    char*  scr    = base;                         base += SZ_SCR;
    float* g      = (float*)base;                 base += SZ_G;
    short* typeWT = (short*)base;                 base += SZ_TWT;
    short* gruWT  = (short*)base;                 base += SZ_GWT;
    short* gruUT  = (short*)base;                 base += SZ_GWT;
    int2*  elist  = (int2*)base;                  base += SZ_LIST;
    int*   meta   = (int*)base;                   // counts[16], offs[17], cursors[16]
    int* counts  = meta;
    int* offs    = meta + 16;
    int* cursors = meta + 33;

    short* transCh = (short*)scr;                 // CH_T*256 bf16 (message phase)
    float* Sch     = (float*)scr;                 // CH_G*768 fp32 (GRU phase)
    float* HHch    = (float*)(scr + (size_t)CH_G * 768 * 4);  // CH_G*256 fp32

    // ---- prep: zero meta, convert weights, bucket edges ----
    zero_meta<<<1, 64, 0, stream>>>(meta, 49);
    cvt_typew<<<(8 * 256 * 256) / 256, 256, 0, stream>>>(type_w, typeWT);
    cvt_gruw<<<(2 * 768 * 256) / 256, 256, 0, stream>>>(gru_W, gruWT);
    cvt_gruw<<<(2 * 768 * 256) / 256, 256, 0, stream>>>(gru_U, gruUT);
    histo_kernel<<<(N_EDGES + 255) / 256, 256, 0, stream>>>(edges, counts);
    scan_kernel<<<1, 1, 0, stream>>>(counts, offs);
    fill_kernel<<<(N_EDGES + 255) / 256, 256, 0, stream>>>(edges, offs, cursors, elist);

    init_h_kernel<<<N_NODES, H, 0, stream>>>(nodes, embed, h);

    const int steps[2] = {3, 1};
    for (int l = 0; l < 2; l++) {
        const short* WT = gruWT + (size_t)l * 768 * 256;
        const short* UT = gruUT + (size_t)l * 768 * 256;
        const float* bi = gru_bi + (size_t)l * 768;
        const float* br = gru_br + (size_t)l * 768;
        for (int s = 0; s < steps[l]; s++) {
            {   // msgs = 0
                int n4 = (int)(SZ_MSG / 16);
                zero_kernel<<<(n4 + 255) / 256, 256, 0, stream>>>((float4*)msgs, n4);
            }
            // message passing: per src-chunk, per type: transform (bf16 out) + bucketed scatter
            for (int c = 0; c < 4; c++) {
                int c0 = c * CH_T;
                for (int t = 0; t < 4; t++) {
                    const short* WTt = typeWT + (size_t)(l * 4 + t) * 256 * 256;
                    const float* bt  = type_b + (size_t)(l * 4 + t) * 256;
                    dim3 grid((CH_T + 127) / 128, 256 / 128);
                    mm_bf16<<<grid, 256, 0, stream>>>(h + (size_t)c0 * H, WTt, bt,
                                                      transCh, CH_T, 256, 0, 1);
                    scatter_kernel<<<4096, 256, 0, stream>>>(elist, offs, c * 4 + t, c0,
                                                             transCh, msgs);
                }
            }
            // GRU in row chunks
            for (int r0 = 0; r0 < N_NODES; r0 += CH_G) {
                dim3 gS((CH_G + 127) / 128, 768 / 128);
                mm_bf16<<<gS, 256, 0, stream>>>(msgs + (size_t)r0 * H, WT, bi,
                                                Sch, CH_G, 768, 0, 0);
                dim3 gU((CH_G + 127) / 128, 512 / 128);
                mm_bf16<<<gU, 256, 0, stream>>>(h + (size_t)r0 * H, UT, br,
                                                Sch, CH_G, 768, 1, 0);
                dim3 gH((CH_G + 127) / 128, 256 / 128);
                mm_bf16<<<gH, 256, 0, stream>>>(h + (size_t)r0 * H, UT + (size_t)512 * 256,
                                                br + 512, HHch, CH_G, 256, 0, 0);
                gru_kernel<<<CH_G, 256, 0, stream>>>(h, Sch, HHch, r0, CH_G);
            }
        }
    }

    gate_kernel<<<(N_NODES * 64) / 256, 256, 0, stream>>>(h, gate_W, gate_b, g);
    out_kernel<<<N_GRAPHS, 256, 0, stream>>>(h, g, gsizes, out_W, out_b, out);
}

// Round 6
// 18620.172 us; speedup vs baseline: 1.3542x; 1.3542x over previous
//
#include <hip/hip_runtime.h>
#include <math.h>

#define N_NODES 100000
#define N_GRAPHS 100
#define N_EDGES 1000000
#define H 256
#define L_POS 512
#define CH 10000      // node chunk for both phases (10 chunks)

typedef short bf16x8 __attribute__((ext_vector_type(8)));
typedef float f32x4  __attribute__((ext_vector_type(4)));

__device__ inline short f2bf(float f) {
    union { float f; unsigned u; } v; v.f = f;
    unsigned r = (v.u + 0x7FFF + ((v.u >> 16) & 1)) >> 16;
    return (short)r;
}
__device__ inline float bf2f(unsigned short u) {
    union { unsigned u; float f; } v; v.u = ((unsigned)u) << 16;
    return v.f;
}

// ---------------- zero fill ----------------
__global__ void zero_kernel(float4* __restrict__ p, int n4)
{
    int i = blockIdx.x * 256 + threadIdx.x;
    if (i < n4) p[i] = make_float4(0.f, 0.f, 0.f, 0.f);
}
__global__ void zero_meta(int* __restrict__ p, int n)
{
    int i = threadIdx.x;
    if (i < n) p[i] = 0;
}

// ---------------- init h ----------------
__global__ void init_h_kernel(const int* __restrict__ nodes,
                              const float* __restrict__ embed,
                              float* __restrict__ h)
{
    int n = blockIdx.x;
    int j = threadIdx.x;
    int tok = nodes[n];
    int p = nodes[N_NODES + n];
    if (p > L_POS) p = L_POS;
    float pe = 0.0f;
    if (p > 0) {
        float pos = (float)(p - 1);
        float denom = powf(10000.0f, 2.0f * (float)j / (float)H);
        float ang = pos / denom;
        pe = (j & 1) ? cosf(ang) : sinf(ang);
    }
    h[(size_t)n * H + j] = embed[(size_t)tok * H + j] + pe;
}

// ---------------- weight prep ----------------
// typeW4[l][n][k] = type_w[l][n>>8][k][n&255]   (n in [0,1024))
__global__ void cvt_typew4(const float* __restrict__ w, short* __restrict__ wt)
{
    int idx = blockIdx.x * 256 + threadIdx.x;
    if (idx >= 2 * 1024 * 256) return;
    int l = idx / (1024 * 256);
    int rem = idx % (1024 * 256);
    int n = rem >> 8, k = rem & 255;
    int t = n >> 8, c = n & 255;
    wt[idx] = f2bf(w[(((size_t)(l * 4 + t)) * 256 + k) * 256 + c]);
}
// Bcomb[l][n][k512]: [msgs|h] @ Bcomb = [S_z|S_r|S_xh|hh]
__global__ void cvt_comb(const float* __restrict__ W, const float* __restrict__ U,
                         short* __restrict__ B)
{
    int idx = blockIdx.x * 256 + threadIdx.x;
    if (idx >= 2 * 1024 * 512) return;
    int l = idx / (1024 * 512);
    int rem = idx % (1024 * 512);
    int n = rem >> 9, k = rem & 511;
    float v = 0.0f;
    if (n < 512) {
        v = (k < 256) ? W[((size_t)l * 256 + k) * 768 + n]
                      : U[((size_t)l * 256 + (k - 256)) * 768 + n];
    } else if (n < 768) {
        if (k < 256) v = W[((size_t)l * 256 + k) * 768 + n];
    } else {
        if (k >= 256) v = U[((size_t)l * 256 + (k - 256)) * 768 + (n - 256)];
    }
    B[idx] = f2bf(v);
}
__global__ void cvt_bias(const float* __restrict__ type_b,
                         const float* __restrict__ bi, const float* __restrict__ br,
                         float* __restrict__ biasT4, float* __restrict__ biasC)
{
    int idx = blockIdx.x * 256 + threadIdx.x;
    if (idx >= 2048) return;
    int l = idx >> 10, n = idx & 1023;
    int t = n >> 8, c = n & 255;
    biasT4[idx] = type_b[(l * 4 + t) * 256 + c];
    float v;
    if (n < 512)      v = bi[l * 768 + n] + br[l * 768 + n];
    else if (n < 768) v = bi[l * 768 + n];
    else              v = br[l * 768 + (n - 256)];
    biasC[idx] = v;
}

// ---------------- edge bucketing: bucket = (src/CH)*4 + etype (40 buckets) ----------------
__global__ void histo_kernel(const int* __restrict__ edges, int* __restrict__ counts)
{
    __shared__ int lc[40];
    if (threadIdx.x < 40) lc[threadIdx.x] = 0;
    __syncthreads();
    int e = blockIdx.x * 256 + threadIdx.x;
    if (e < N_EDGES) {
        int t = edges[e * 3];
        int s = edges[e * 3 + 1];
        atomicAdd(&lc[(s / CH) * 4 + t], 1);
    }
    __syncthreads();
    if (threadIdx.x < 40 && lc[threadIdx.x]) atomicAdd(&counts[threadIdx.x], lc[threadIdx.x]);
}
__global__ void scan_kernel(const int* __restrict__ counts, int* __restrict__ offs)
{
    if (blockIdx.x == 0 && threadIdx.x == 0) {
        int acc = 0;
        for (int i = 0; i < 40; i++) { offs[i] = acc; acc += counts[i]; }
        offs[40] = acc;
    }
}
// list entry: (src | t<<17, tgt)
__global__ void fill_kernel(const int* __restrict__ edges, const int* __restrict__ offs,
                            int* __restrict__ cursors, int2* __restrict__ list)
{
    int e = blockIdx.x * 256 + threadIdx.x;
    if (e >= N_EDGES) return;
    int t = edges[e * 3];
    int s = edges[e * 3 + 1];
    int tg = edges[e * 3 + 2];
    int b = (s / CH) * 4 + t;
    int p = atomicAdd(&cursors[b], 1);
    list[offs[b] + p] = make_int2(s | (t << 17), tg);
}

// ---- bf16 MFMA matmul: C(nrows x 1024, bf16) = bf16([A0|A1] fp32) @ BT^T + bias
// A0,A1: fp32 row-major, 256 cols each (A1 null if Ktot==256). BT: bf16 [n][Ktot].
__global__ __launch_bounds__(256) void mm_bf16(
    const float* __restrict__ A0, const float* __restrict__ A1,
    const short* __restrict__ BT, const float* __restrict__ bias,
    short* __restrict__ C, int nrows, int ldc, int Ktot)
{
    __shared__ short As[128 * 40];
    __shared__ short Bs[128 * 40];
    const int tid = threadIdx.x;
    const int bm = blockIdx.x * 128;
    const int bn = blockIdx.y * 128;
    const int lane = tid & 63;
    const int wave = tid >> 6;
    const int wm = (wave >> 1) * 64;
    const int wn = (wave & 1) * 64;
    const int q = lane >> 4;
    const int r16 = lane & 15;

    f32x4 acc[4][4];
    #pragma unroll
    for (int i = 0; i < 4; i++)
        #pragma unroll
        for (int j = 0; j < 4; j++)
            acc[i][j] = (f32x4){0.f, 0.f, 0.f, 0.f};

    const int srow = tid >> 1;         // 0..127
    const int skh  = (tid & 1) * 16;   // 0 or 16
    const int agr  = bm + srow;
    const bool aok = agr < nrows;
    const short* Bp = BT + (size_t)(bn + srow) * Ktot + skh;

    for (int k0 = 0; k0 < Ktot; k0 += 32) {
        const float* Ap = (k0 < 256)
            ? A0 + (size_t)agr * 256 + k0 + skh
            : A1 + (size_t)agr * 256 + (k0 - 256) + skh;
        short tmp[16];
        if (aok) {
            #pragma unroll
            for (int i = 0; i < 4; i++) {
                float4 v = *(const float4*)(Ap + i * 4);
                tmp[i*4+0] = f2bf(v.x); tmp[i*4+1] = f2bf(v.y);
                tmp[i*4+2] = f2bf(v.z); tmp[i*4+3] = f2bf(v.w);
            }
        } else {
            #pragma unroll
            for (int i = 0; i < 16; i++) tmp[i] = 0;
        }
        uint4 b0 = *(const uint4*)(Bp + k0);
        uint4 b1 = *(const uint4*)(Bp + k0 + 8);

        __syncthreads();
        *(bf16x8*)&As[srow * 40 + skh]     = *(bf16x8*)&tmp[0];
        *(bf16x8*)&As[srow * 40 + skh + 8] = *(bf16x8*)&tmp[8];
        *(uint4*)&Bs[srow * 40 + skh]      = b0;
        *(uint4*)&Bs[srow * 40 + skh + 8]  = b1;
        __syncthreads();

        bf16x8 af[4], bfr[4];
        #pragma unroll
        for (int mt = 0; mt < 4; mt++)
            af[mt] = *(const bf16x8*)&As[(wm + mt * 16 + r16) * 40 + q * 8];
        #pragma unroll
        for (int nt = 0; nt < 4; nt++)
            bfr[nt] = *(const bf16x8*)&Bs[(wn + nt * 16 + r16) * 40 + q * 8];
        #pragma unroll
        for (int mt = 0; mt < 4; mt++)
            #pragma unroll
            for (int nt = 0; nt < 4; nt++)
                acc[mt][nt] = __builtin_amdgcn_mfma_f32_16x16x32_bf16(af[mt], bfr[nt], acc[mt][nt], 0, 0, 0);
    }

    #pragma unroll
    for (int mt = 0; mt < 4; mt++) {
        #pragma unroll
        for (int reg = 0; reg < 4; reg++) {
            int row = bm + wm + mt * 16 + q * 4 + reg;
            if (row >= nrows) continue;
            #pragma unroll
            for (int nt = 0; nt < 4; nt++) {
                int col = bn + wn + nt * 16 + r16;
                C[(size_t)row * ldc + col] = f2bf(acc[mt][nt][reg] + bias[col]);
            }
        }
    }
}

// ---- chunk scatter over 4 buckets: msgs[tgt] += fp32(trans4[src-c0][t*256..]) ----
__global__ __launch_bounds__(256) void scatter_kernel(const int2* __restrict__ list,
                                                      const int* __restrict__ offs,
                                                      int chunk, int c0,
                                                      const short* __restrict__ trans4,
                                                      float* __restrict__ msgs)
{
    int off = offs[chunk * 4];
    int cnt = offs[chunk * 4 + 4] - off;
    int w = (blockIdx.x * 256 + threadIdx.x) >> 6;
    int lane = threadIdx.x & 63;
    int nw = (gridDim.x * 256) >> 6;
    for (int e = w; e < cnt; e += nw) {
        int2 st = list[off + e];
        int src = st.x & 0x1FFFF;
        int t = st.x >> 17;
        const short* trow = trans4 + (size_t)(src - c0) * 1024 + t * 256 + lane * 4;
        uint2 pk = *(const uint2*)trow;
        float* dst = msgs + (size_t)st.y * H + lane * 4;
        unsafeAtomicAdd(dst + 0, bf2f((unsigned short)(pk.x & 0xFFFF)));
        unsafeAtomicAdd(dst + 1, bf2f((unsigned short)(pk.x >> 16)));
        unsafeAtomicAdd(dst + 2, bf2f((unsigned short)(pk.y & 0xFFFF)));
        unsafeAtomicAdd(dst + 3, bf2f((unsigned short)(pk.y >> 16)));
    }
}

// ---- GRU elementwise: S rows [z|r|xh|hh] (1024, bf16); h fp32 in place ----
__global__ void gru_kernel(float* __restrict__ h, const short* __restrict__ S,
                           int r0, int nrows)
{
    int nl = blockIdx.x;
    if (nl >= nrows) return;
    int j = threadIdx.x;
    int n = r0 + nl;
    const short* Srow = S + (size_t)nl * 1024;
    float sz = bf2f((unsigned short)Srow[j]);
    float sr = bf2f((unsigned short)Srow[256 + j]);
    float xh = bf2f((unsigned short)Srow[512 + j]);
    float hh = bf2f((unsigned short)Srow[768 + j]);
    size_t idx = (size_t)n * H + j;
    float hv = h[idx];
    float z = 1.0f / (1.0f + expf(-sz));
    float r = 1.0f / (1.0f + expf(-sr));
    float cand = tanhf(xh + r * hh);
    h[idx] = z * hv + (1.0f - z) * cand;
}

// ---------------- gate logits ----------------
__global__ __launch_bounds__(256) void gate_kernel(const float* __restrict__ h,
                                                   const float* __restrict__ gW,
                                                   const float* __restrict__ gb,
                                                   float* __restrict__ g)
{
    int tid = blockIdx.x * 256 + threadIdx.x;
    int n = tid >> 6;
    if (n >= N_NODES) return;
    int lane = tid & 63;
    float s = 0.0f;
    #pragma unroll
    for (int j = 0; j < 4; j++)
        s += h[(size_t)n * H + lane + j * 64] * gW[lane + j * 64];
    #pragma unroll
    for (int off = 32; off > 0; off >>= 1)
        s += __shfl_down(s, off);
    if (lane == 0) g[n] = s + gb[0];
}

// ---------------- per-graph softmax-gated readout ----------------
__global__ __launch_bounds__(256) void out_kernel(const float* __restrict__ h,
                                                  const float* __restrict__ g,
                                                  const int* __restrict__ sizes,
                                                  const float* __restrict__ outW,
                                                  const float* __restrict__ outB,
                                                  float* __restrict__ out)
{
    __shared__ float red[256];
    int gid = blockIdx.x;
    int tid = threadIdx.x;

    int start = 0, end = 0;
    {
        int c = 0;
        for (int i = 0; i < N_GRAPHS; i++) {
            int sz = sizes[i];
            if (i == gid) { start = c; end = c + sz; }
            c += sz;
        }
    }

    float m = -INFINITY;
    for (int n = start + tid; n < end; n += 256) m = fmaxf(m, g[n]);
    red[tid] = m; __syncthreads();
    for (int s = 128; s > 0; s >>= 1) {
        if (tid < s) red[tid] = fmaxf(red[tid], red[tid + s]);
        __syncthreads();
    }
    m = red[0]; __syncthreads();

    float s_ = 0.0f;
    for (int n = start + tid; n < end; n += 256) s_ += expf(g[n] - m);
    red[tid] = s_; __syncthreads();
    for (int s = 128; s > 0; s >>= 1) {
        if (tid < s) red[tid] += red[tid + s];
        __syncthreads();
    }
    float ssum = red[0]; __syncthreads();

    float acc = 0.0f;
    for (int n = start; n < end; n++) {
        float e = expf(g[n] - m);
        acc += e * h[(size_t)n * H + tid];
    }

    float inv = 1.0f / (ssum + 1e-16f);
    for (int c = 0; c < 2; c++) {
        red[tid] = acc * outW[tid * 2 + c];
        __syncthreads();
        for (int s = 128; s > 0; s >>= 1) {
            if (tid < s) red[tid] += red[tid + s];
            __syncthreads();
        }
        if (tid == 0) out[gid * 2 + c] = red[0] * inv + outB[c] * (ssum * inv);
        __syncthreads();
    }
}

extern "C" void kernel_launch(void* const* d_in, const int* in_sizes, int n_in,
                              void* d_out, int out_size, void* d_ws, size_t ws_size,
                              hipStream_t stream)
{
    const int*   nodes  = (const int*)d_in[0];
    const int*   gsizes = (const int*)d_in[1];
    const int*   edges  = (const int*)d_in[2];
    const float* embed  = (const float*)d_in[3];
    const float* type_w = (const float*)d_in[4];
    const float* type_b = (const float*)d_in[5];
    const float* gru_W  = (const float*)d_in[6];
    const float* gru_U  = (const float*)d_in[7];
    const float* gru_bi = (const float*)d_in[8];
    const float* gru_br = (const float*)d_in[9];
    const float* gate_W = (const float*)d_in[10];
    const float* gate_b = (const float*)d_in[11];
    const float* out_W  = (const float*)d_in[12];
    const float* out_b  = (const float*)d_in[13];
    float* out = (float*)d_out;

    // ---- workspace layout (bytes), total ~236.8 MB ----
    const size_t SZ_H    = (size_t)N_NODES * H * 4;         // 102.4 MB
    const size_t SZ_MSG  = SZ_H;                             // 102.4 MB
    const size_t SZ_SCR  = (size_t)CH * 1024 * 2;            // 20.48 MB (trans4 / Sch, bf16)
    const size_t SZ_G    = (size_t)N_NODES * 4;              // 0.4 MB
    const size_t SZ_TW4  = (size_t)2 * 1024 * 256 * 2;       // 1.05 MB
    const size_t SZ_BC   = (size_t)2 * 1024 * 512 * 2;       // 2.10 MB
    const size_t SZ_BIAS = (size_t)2 * 1024 * 4;             // 8 KB each
    const size_t SZ_LIST = (size_t)N_EDGES * 8;              // 8 MB
    const size_t SZ_META = 512;
    size_t need = SZ_H + SZ_MSG + SZ_SCR + SZ_G + SZ_TW4 + SZ_BC + 2 * SZ_BIAS + SZ_LIST + SZ_META;
    if (ws_size < need) return;   // clean fail, not a crash

    char* base = (char*)d_ws;
    float* h      = (float*)base;  base += SZ_H;
    float* msgs   = (float*)base;  base += SZ_MSG;
    char*  scr    = base;          base += SZ_SCR;
    float* g      = (float*)base;  base += SZ_G;
    short* typeW4 = (short*)base;  base += SZ_TW4;
    short* Bcomb  = (short*)base;  base += SZ_BC;
    float* biasT4 = (float*)base;  base += SZ_BIAS;
    float* biasC  = (float*)base;  base += SZ_BIAS;
    int2*  elist  = (int2*)base;   base += SZ_LIST;
    int*   meta   = (int*)base;    // counts[40], offs[41], cursors[40]
    int* counts  = meta;
    int* offs    = meta + 40;
    int* cursors = meta + 81;

    short* trans4 = (short*)scr;   // CH x 1024 bf16 (message phase)
    short* Sch    = (short*)scr;   // CH x 1024 bf16 (GRU phase)

    // ---- prep ----
    zero_meta<<<1, 128, 0, stream>>>(meta, 121);
    cvt_typew4<<<(2 * 1024 * 256) / 256, 256, 0, stream>>>(type_w, typeW4);
    cvt_comb<<<(2 * 1024 * 512) / 256, 256, 0, stream>>>(gru_W, gru_U, Bcomb);
    cvt_bias<<<8, 256, 0, stream>>>(type_b, gru_bi, gru_br, biasT4, biasC);
    histo_kernel<<<(N_EDGES + 255) / 256, 256, 0, stream>>>(edges, counts);
    scan_kernel<<<1, 1, 0, stream>>>(counts, offs);
    fill_kernel<<<(N_EDGES + 255) / 256, 256, 0, stream>>>(edges, offs, cursors, elist);
    init_h_kernel<<<N_NODES, H, 0, stream>>>(nodes, embed, h);

    const int steps[2] = {3, 1};
    for (int l = 0; l < 2; l++) {
        const short* TW = typeW4 + (size_t)l * 1024 * 256;
        const float* Tb = biasT4 + (size_t)l * 1024;
        const short* BC = Bcomb + (size_t)l * 1024 * 512;
        const float* Cb = biasC + (size_t)l * 1024;
        for (int s = 0; s < steps[l]; s++) {
            {   // msgs = 0
                int n4 = (int)(SZ_MSG / 16);
                zero_kernel<<<(n4 + 255) / 256, 256, 0, stream>>>((float4*)msgs, n4);
            }
            // message passing: per chunk: 4-type transform (N=1024) + 4-bucket scatter
            for (int c = 0; c < N_NODES / CH; c++) {
                int c0 = c * CH;
                dim3 grid((CH + 127) / 128, 1024 / 128);
                mm_bf16<<<grid, 256, 0, stream>>>(h + (size_t)c0 * H, nullptr, TW, Tb,
                                                  trans4, CH, 1024, 256);
                scatter_kernel<<<2048, 256, 0, stream>>>(elist, offs, c, c0, trans4, msgs);
            }
            // GRU: per chunk: ONE combined K=512 matmul + elementwise
            for (int c = 0; c < N_NODES / CH; c++) {
                int c0 = c * CH;
                dim3 grid((CH + 127) / 128, 1024 / 128);
                mm_bf16<<<grid, 256, 0, stream>>>(msgs + (size_t)c0 * H, h + (size_t)c0 * H,
                                                  BC, Cb, Sch, CH, 1024, 512);
                gru_kernel<<<CH, 256, 0, stream>>>(h, Sch, c0, CH);
            }
        }
    }

    gate_kernel<<<(N_NODES * 64) / 256, 256, 0, stream>>>(h, gate_W, gate_b, g);
    out_kernel<<<N_GRAPHS, 256, 0, stream>>>(h, g, gsizes, out_W, out_b, out);
}

// Round 7
// 4024.035 us; speedup vs baseline: 6.2662x; 4.6272x over previous
//
#include <hip/hip_runtime.h>
#include <math.h>

#define N_NODES 100000
#define N_GRAPHS 100
#define N_EDGES 1000000
#define H 256
#define L_POS 512
#define CH 20000        // node chunk (5 chunks)
#define NBUCK (4 * N_NODES)
#define NBLK ((NBUCK + 255) / 256)   // 1563 scan blocks

typedef short bf16x8 __attribute__((ext_vector_type(8)));
typedef float f32x4  __attribute__((ext_vector_type(4)));

__device__ inline short f2bf(float f) {
    union { float f; unsigned u; } v; v.f = f;
    unsigned r = (v.u + 0x7FFF + ((v.u >> 16) & 1)) >> 16;
    return (short)r;
}
__device__ inline float bf2f(unsigned short u) {
    union { unsigned u; float f; } v; v.u = ((unsigned)u) << 16;
    return v.f;
}

// ---------------- zero ints (int4) ----------------
__global__ void zero_int(int4* __restrict__ p, int n4)
{
    int i = blockIdx.x * 256 + threadIdx.x;
    if (i < n4) p[i] = make_int4(0, 0, 0, 0);
}

// ---------------- init h ----------------
__global__ void init_h_kernel(const int* __restrict__ nodes,
                              const float* __restrict__ embed,
                              float* __restrict__ h)
{
    int n = blockIdx.x;
    int j = threadIdx.x;
    int tok = nodes[n];
    int p = nodes[N_NODES + n];
    if (p > L_POS) p = L_POS;
    float pe = 0.0f;
    if (p > 0) {
        float pos = (float)(p - 1);
        float denom = powf(10000.0f, 2.0f * (float)j / (float)H);
        float ang = pos / denom;
        pe = (j & 1) ? cosf(ang) : sinf(ang);
    }
    h[(size_t)n * H + j] = embed[(size_t)tok * H + j] + pe;
}

// ---------------- weight prep ----------------
// Wstack BT layout: [l][n][k=1024], k = t*256+kk: BT = type_w[l][t][kk][n]
__global__ void cvt_wstack(const float* __restrict__ w, short* __restrict__ wt)
{
    int idx = blockIdx.x * 256 + threadIdx.x;
    if (idx >= 2 * 256 * 1024) return;
    int l = idx / (256 * 1024);
    int rem = idx % (256 * 1024);
    int n = rem >> 10, k = rem & 1023;
    int t = k >> 8, kk = k & 255;
    wt[idx] = f2bf(w[(((size_t)(l * 4 + t)) * 256 + kk) * 256 + n]);
}
// Bcomb[l][n][k512]: [msgs|h] @ Bcomb = [S_z|S_r|S_xh|hh]
__global__ void cvt_comb(const float* __restrict__ W, const float* __restrict__ U,
                         short* __restrict__ B)
{
    int idx = blockIdx.x * 256 + threadIdx.x;
    if (idx >= 2 * 1024 * 512) return;
    int l = idx / (1024 * 512);
    int rem = idx % (1024 * 512);
    int n = rem >> 9, k = rem & 511;
    float v = 0.0f;
    if (n < 512) {
        v = (k < 256) ? W[((size_t)l * 256 + k) * 768 + n]
                      : U[((size_t)l * 256 + (k - 256)) * 768 + n];
    } else if (n < 768) {
        if (k < 256) v = W[((size_t)l * 256 + k) * 768 + n];
    } else {
        if (k >= 256) v = U[((size_t)l * 256 + (k - 256)) * 768 + (n - 256)];
    }
    B[idx] = f2bf(v);
}
__global__ void cvt_bias(const float* __restrict__ bi, const float* __restrict__ br,
                         float* __restrict__ biasC)
{
    int idx = blockIdx.x * 256 + threadIdx.x;
    if (idx >= 2048) return;
    int l = idx >> 10, n = idx & 1023;
    float v;
    if (n < 512)      v = bi[l * 768 + n] + br[l * 768 + n];
    else if (n < 768) v = bi[l * 768 + n];
    else              v = br[l * 768 + (n - 256)];
    biasC[idx] = v;
}

// ---------------- CSR build: bucket = etype*N_NODES + tgt ----------------
__global__ void histo_kernel(const int* __restrict__ edges, int* __restrict__ counts)
{
    int e = blockIdx.x * 256 + threadIdx.x;
    if (e >= N_EDGES) return;
    int t = edges[e * 3];
    int tg = edges[e * 3 + 2];
    atomicAdd(&counts[t * N_NODES + tg], 1);
}
// scan phase 1: per-block sums
__global__ void scan1(const int* __restrict__ counts, int* __restrict__ partial)
{
    __shared__ int s[256];
    int i = blockIdx.x * 256 + threadIdx.x;
    s[threadIdx.x] = (i < NBUCK) ? counts[i] : 0;
    __syncthreads();
    for (int off = 128; off > 0; off >>= 1) {
        if (threadIdx.x < off) s[threadIdx.x] += s[threadIdx.x + off];
        __syncthreads();
    }
    if (threadIdx.x == 0) partial[blockIdx.x] = s[0];
}
// scan phase 2: exclusive scan of partials (single thread; 1563 iters)
__global__ void scan2(int* __restrict__ partial, int* __restrict__ offs)
{
    if (threadIdx.x == 0 && blockIdx.x == 0) {
        int run = 0;
        for (int i = 0; i < NBLK; i++) { int v = partial[i]; partial[i] = run; run += v; }
        offs[NBUCK] = run;
    }
}
// scan phase 3: intra-block exclusive scan + add block prefix
__global__ void scan3(const int* __restrict__ counts, const int* __restrict__ partial,
                      int* __restrict__ offs)
{
    __shared__ int s[256];
    int i = blockIdx.x * 256 + threadIdx.x;
    int v = (i < NBUCK) ? counts[i] : 0;
    s[threadIdx.x] = v;
    __syncthreads();
    for (int off = 1; off < 256; off <<= 1) {
        int add = (threadIdx.x >= off) ? s[threadIdx.x - off] : 0;
        __syncthreads();
        s[threadIdx.x] += add;
        __syncthreads();
    }
    if (i < NBUCK) offs[i] = partial[blockIdx.x] + s[threadIdx.x] - v;
}
__global__ void fill_kernel(const int* __restrict__ edges, const int* __restrict__ offs,
                            int* __restrict__ cursors, int* __restrict__ srcs)
{
    int e = blockIdx.x * 256 + threadIdx.x;
    if (e >= N_EDGES) return;
    int t = edges[e * 3];
    int s = edges[e * 3 + 1];
    int tg = edges[e * 3 + 2];
    int b = t * N_NODES + tg;
    int p = atomicAdd(&cursors[b], 1);
    srcs[offs[b] + p] = s;
}

// ---- gather: gath4[tgt-c0][t*256+col] = bf16( sum_{e in CSR(t,tgt)} h[src][col] ) ----
__global__ __launch_bounds__(256) void gather_kernel(
    const int* __restrict__ offs, const int* __restrict__ srcs,
    const float* __restrict__ h, short* __restrict__ gath4, int c0)
{
    int w = (blockIdx.x * 256 + threadIdx.x) >> 6;   // local tgt in [0,CH)
    int lane = threadIdx.x & 63;
    if (w >= CH) return;
    int tgt = c0 + w;
    int col = lane * 4;
    #pragma unroll
    for (int t = 0; t < 4; t++) {
        int b = t * N_NODES + tgt;
        int e0 = offs[b], e1 = offs[b + 1];
        float4 acc = make_float4(0.f, 0.f, 0.f, 0.f);
        for (int e = e0; e < e1; e++) {
            int src = srcs[e];
            float4 v = *(const float4*)(h + (size_t)src * H + col);
            acc.x += v.x; acc.y += v.y; acc.z += v.z; acc.w += v.w;
        }
        unsigned p0 = ((unsigned)(unsigned short)f2bf(acc.x)) |
                      (((unsigned)(unsigned short)f2bf(acc.y)) << 16);
        unsigned p1 = ((unsigned)(unsigned short)f2bf(acc.z)) |
                      (((unsigned)(unsigned short)f2bf(acc.w)) << 16);
        *(uint2*)(gath4 + (size_t)w * 1024 + t * 256 + col) = make_uint2(p0, p1);
    }
}

// ---- bf16 MFMA matmul: C(nrows x gridDim.y*128, bf16) = [A0 bf16 | A1 fp32] @ BT^T + bias
// A0: bf16, row-stride s0, covers k < K0. A1: fp32, row-stride 256, covers k >= K0.
// cnt != null: bias = Sum_t cnt[t*N + c0 + row] * bias[t*256 + col]  (message epilogue)
__global__ __launch_bounds__(256) void mm_bf16(
    const short* __restrict__ A0, int s0, int K0,
    const float* __restrict__ A1,
    const short* __restrict__ BT, int Ktot,
    const float* __restrict__ bias,
    const int* __restrict__ cnt, int c0,
    short* __restrict__ C, int ldc, int nrows)
{
    __shared__ short As[128 * 40];
    __shared__ short Bs[128 * 40];
    const int tid = threadIdx.x;
    const int bm = blockIdx.x * 128;
    const int bn = blockIdx.y * 128;
    const int lane = tid & 63;
    const int wave = tid >> 6;
    const int wm = (wave >> 1) * 64;
    const int wn = (wave & 1) * 64;
    const int q = lane >> 4;
    const int r16 = lane & 15;

    f32x4 acc[4][4];
    #pragma unroll
    for (int i = 0; i < 4; i++)
        #pragma unroll
        for (int j = 0; j < 4; j++)
            acc[i][j] = (f32x4){0.f, 0.f, 0.f, 0.f};

    const int srow = tid >> 1;
    const int skh  = (tid & 1) * 16;
    const int agr  = bm + srow;
    const bool aok = agr < nrows;
    const short* Bp = BT + (size_t)(bn + srow) * Ktot + skh;

    for (int k0 = 0; k0 < Ktot; k0 += 32) {
        uint4 av0, av1;
        if (!aok) {
            av0 = make_uint4(0, 0, 0, 0); av1 = make_uint4(0, 0, 0, 0);
        } else if (k0 < K0) {
            const short* Ap = A0 + (size_t)agr * s0 + k0 + skh;
            av0 = *(const uint4*)Ap;
            av1 = *(const uint4*)(Ap + 8);
        } else {
            const float* Ap = A1 + (size_t)agr * 256 + (k0 - K0) + skh;
            short tmp[16];
            #pragma unroll
            for (int i = 0; i < 4; i++) {
                float4 v = *(const float4*)(Ap + i * 4);
                tmp[i*4+0] = f2bf(v.x); tmp[i*4+1] = f2bf(v.y);
                tmp[i*4+2] = f2bf(v.z); tmp[i*4+3] = f2bf(v.w);
            }
            av0 = *(uint4*)&tmp[0];
            av1 = *(uint4*)&tmp[8];
        }
        uint4 b0 = *(const uint4*)(Bp + k0);
        uint4 b1 = *(const uint4*)(Bp + k0 + 8);

        __syncthreads();
        *(uint4*)&As[srow * 40 + skh]     = av0;
        *(uint4*)&As[srow * 40 + skh + 8] = av1;
        *(uint4*)&Bs[srow * 40 + skh]     = b0;
        *(uint4*)&Bs[srow * 40 + skh + 8] = b1;
        __syncthreads();

        bf16x8 af[4], bfr[4];
        #pragma unroll
        for (int mt = 0; mt < 4; mt++)
            af[mt] = *(const bf16x8*)&As[(wm + mt * 16 + r16) * 40 + q * 8];
        #pragma unroll
        for (int nt = 0; nt < 4; nt++)
            bfr[nt] = *(const bf16x8*)&Bs[(wn + nt * 16 + r16) * 40 + q * 8];
        #pragma unroll
        for (int mt = 0; mt < 4; mt++)
            #pragma unroll
            for (int nt = 0; nt < 4; nt++)
                acc[mt][nt] = __builtin_amdgcn_mfma_f32_16x16x32_bf16(af[mt], bfr[nt], acc[mt][nt], 0, 0, 0);
    }

    #pragma unroll
    for (int mt = 0; mt < 4; mt++) {
        #pragma unroll
        for (int reg = 0; reg < 4; reg++) {
            int row = bm + wm + mt * 16 + q * 4 + reg;
            if (row >= nrows) continue;
            #pragma unroll
            for (int nt = 0; nt < 4; nt++) {
                int col = bn + wn + nt * 16 + r16;
                float v = acc[mt][nt][reg];
                if (cnt) {
                    #pragma unroll
                    for (int t = 0; t < 4; t++)
                        v += (float)cnt[t * N_NODES + c0 + row] * bias[t * 256 + col];
                } else {
                    v += bias[col];
                }
                C[(size_t)row * ldc + col] = f2bf(v);
            }
        }
    }
}

// ---- GRU elementwise: S rows [z|r|xh|hh] (1024, bf16); h fp32 in place ----
__global__ void gru_kernel(float* __restrict__ h, const short* __restrict__ S,
                           int r0, int nrows)
{
    int nl = blockIdx.x;
    if (nl >= nrows) return;
    int j = threadIdx.x;
    int n = r0 + nl;
    const short* Srow = S + (size_t)nl * 1024;
    float sz = bf2f((unsigned short)Srow[j]);
    float sr = bf2f((unsigned short)Srow[256 + j]);
    float xh = bf2f((unsigned short)Srow[512 + j]);
    float hh = bf2f((unsigned short)Srow[768 + j]);
    size_t idx = (size_t)n * H + j;
    float hv = h[idx];
    float z = 1.0f / (1.0f + expf(-sz));
    float r = 1.0f / (1.0f + expf(-sr));
    float cand = tanhf(xh + r * hh);
    h[idx] = z * hv + (1.0f - z) * cand;
}

// ---------------- gate logits ----------------
__global__ __launch_bounds__(256) void gate_kernel(const float* __restrict__ h,
                                                   const float* __restrict__ gW,
                                                   const float* __restrict__ gb,
                                                   float* __restrict__ g)
{
    int tid = blockIdx.x * 256 + threadIdx.x;
    int n = tid >> 6;
    if (n >= N_NODES) return;
    int lane = tid & 63;
    float s = 0.0f;
    #pragma unroll
    for (int j = 0; j < 4; j++)
        s += h[(size_t)n * H + lane + j * 64] * gW[lane + j * 64];
    #pragma unroll
    for (int off = 32; off > 0; off >>= 1)
        s += __shfl_down(s, off);
    if (lane == 0) g[n] = s + gb[0];
}

// ---------------- per-graph softmax-gated readout ----------------
__global__ __launch_bounds__(256) void out_kernel(const float* __restrict__ h,
                                                  const float* __restrict__ g,
                                                  const int* __restrict__ sizes,
                                                  const float* __restrict__ outW,
                                                  const float* __restrict__ outB,
                                                  float* __restrict__ out)
{
    __shared__ float red[256];
    int gid = blockIdx.x;
    int tid = threadIdx.x;

    int start = 0, end = 0;
    {
        int c = 0;
        for (int i = 0; i < N_GRAPHS; i++) {
            int sz = sizes[i];
            if (i == gid) { start = c; end = c + sz; }
            c += sz;
        }
    }

    float m = -INFINITY;
    for (int n = start + tid; n < end; n += 256) m = fmaxf(m, g[n]);
    red[tid] = m; __syncthreads();
    for (int s = 128; s > 0; s >>= 1) {
        if (tid < s) red[tid] = fmaxf(red[tid], red[tid + s]);
        __syncthreads();
    }
    m = red[0]; __syncthreads();

    float s_ = 0.0f;
    for (int n = start + tid; n < end; n += 256) s_ += expf(g[n] - m);
    red[tid] = s_; __syncthreads();
    for (int s = 128; s > 0; s >>= 1) {
        if (tid < s) red[tid] += red[tid + s];
        __syncthreads();
    }
    float ssum = red[0]; __syncthreads();

    float acc = 0.0f;
    for (int n = start; n < end; n++) {
        float e = expf(g[n] - m);
        acc += e * h[(size_t)n * H + tid];
    }

    float inv = 1.0f / (ssum + 1e-16f);
    for (int c = 0; c < 2; c++) {
        red[tid] = acc * outW[tid * 2 + c];
        __syncthreads();
        for (int s = 128; s > 0; s >>= 1) {
            if (tid < s) red[tid] += red[tid + s];
            __syncthreads();
        }
        if (tid == 0) out[gid * 2 + c] = red[0] * inv + outB[c] * (ssum * inv);
        __syncthreads();
    }
}

static inline size_t alup(size_t x) { return (x + 255) & ~(size_t)255; }

extern "C" void kernel_launch(void* const* d_in, const int* in_sizes, int n_in,
                              void* d_out, int out_size, void* d_ws, size_t ws_size,
                              hipStream_t stream)
{
    const int*   nodes  = (const int*)d_in[0];
    const int*   gsizes = (const int*)d_in[1];
    const int*   edges  = (const int*)d_in[2];
    const float* embed  = (const float*)d_in[3];
    const float* type_w = (const float*)d_in[4];
    const float* type_b = (const float*)d_in[5];
    const float* gru_W  = (const float*)d_in[6];
    const float* gru_U  = (const float*)d_in[7];
    const float* gru_bi = (const float*)d_in[8];
    const float* gru_br = (const float*)d_in[9];
    const float* gate_W = (const float*)d_in[10];
    const float* gate_b = (const float*)d_in[11];
    const float* out_W  = (const float*)d_in[12];
    const float* out_b  = (const float*)d_in[13];
    float* out = (float*)d_out;

    // ---- workspace layout (bytes), total ~207 MB ----
    const size_t SZ_H    = alup((size_t)N_NODES * H * 4);      // 102.4 MB fp32
    const size_t SZ_MSG  = alup((size_t)N_NODES * H * 2);      // 51.2 MB bf16
    const size_t SZ_SCR  = alup((size_t)CH * 1024 * 2);        // 40.96 MB bf16 (gath4 / Sch)
    const size_t SZ_G    = alup((size_t)N_NODES * 4);
    const size_t SZ_WST  = alup((size_t)2 * 256 * 1024 * 2);   // 1.05 MB
    const size_t SZ_BC   = alup((size_t)2 * 1024 * 512 * 2);   // 2.10 MB
    const size_t SZ_BIAS = alup((size_t)2 * 1024 * 4);
    const size_t SZ_CNT  = alup((size_t)NBUCK * 4);            // 1.6 MB
    const size_t SZ_CUR  = SZ_CNT;
    const size_t SZ_OFF  = alup((size_t)(NBUCK + 1) * 4);
    const size_t SZ_SRC  = alup((size_t)N_EDGES * 4);          // 4 MB
    const size_t SZ_PART = alup((size_t)NBLK * 4);
    size_t need = SZ_H + SZ_MSG + SZ_SCR + SZ_G + SZ_WST + SZ_BC + SZ_BIAS +
                  SZ_CNT + SZ_CUR + SZ_OFF + SZ_SRC + SZ_PART;
    if (ws_size < need) return;   // clean fail, not a crash

    char* base = (char*)d_ws;
    float* h      = (float*)base;  base += SZ_H;
    short* msgs   = (short*)base;  base += SZ_MSG;
    short* scr    = (short*)base;  base += SZ_SCR;   // gath4 (msg) / Sch (gru)
    float* g      = (float*)base;  base += SZ_G;
    short* Wstack = (short*)base;  base += SZ_WST;
    short* Bcomb  = (short*)base;  base += SZ_BC;
    float* biasC  = (float*)base;  base += SZ_BIAS;
    int*   counts = (int*)base;    base += SZ_CNT;
    int*   cursors= (int*)base;    base += SZ_CUR;
    int*   offs   = (int*)base;    base += SZ_OFF;
    int*   srcs   = (int*)base;    base += SZ_SRC;
    int*   partial= (int*)base;    base += SZ_PART;

    // ---- prep: weights, CSR by (type,tgt) ----
    cvt_wstack<<<(2 * 256 * 1024) / 256, 256, 0, stream>>>(type_w, Wstack);
    cvt_comb<<<(2 * 1024 * 512) / 256, 256, 0, stream>>>(gru_W, gru_U, Bcomb);
    cvt_bias<<<8, 256, 0, stream>>>(gru_bi, gru_br, biasC);
    {   // zero counts+cursors (contiguous)
        int n4 = (int)((SZ_CNT + SZ_CUR) / 16);
        zero_int<<<(n4 + 255) / 256, 256, 0, stream>>>((int4*)counts, n4);
    }
    histo_kernel<<<(N_EDGES + 255) / 256, 256, 0, stream>>>(edges, counts);
    scan1<<<NBLK, 256, 0, stream>>>(counts, partial);
    scan2<<<1, 64, 0, stream>>>(partial, offs);
    scan3<<<NBLK, 256, 0, stream>>>(counts, partial, offs);
    fill_kernel<<<(N_EDGES + 255) / 256, 256, 0, stream>>>(edges, offs, cursors, srcs);
    init_h_kernel<<<N_NODES, H, 0, stream>>>(nodes, embed, h);

    const int steps[2] = {3, 1};
    for (int l = 0; l < 2; l++) {
        const short* WS = Wstack + (size_t)l * 256 * 1024;
        const float* Tb = type_b + (size_t)l * 4 * 256;   // [4][256] fp32
        const short* BC = Bcomb + (size_t)l * 1024 * 512;
        const float* Cb = biasC + (size_t)l * 1024;
        for (int s = 0; s < steps[l]; s++) {
            // message pass: per chunk: gather 4 types -> one K=1024 matmul -> msgs (bf16)
            for (int c = 0; c < N_NODES / CH; c++) {
                int c0 = c * CH;
                gather_kernel<<<CH / 4, 256, 0, stream>>>(offs, srcs, h, scr, c0);
                dim3 grid((CH + 127) / 128, 256 / 128);
                mm_bf16<<<grid, 256, 0, stream>>>(scr, 1024, 1024, nullptr,
                                                  WS, 1024, Tb, counts, c0,
                                                  msgs + (size_t)c0 * H, H, CH);
            }
            // GRU: per chunk: one combined K=512 matmul ([msgs bf16 | h fp32]) + elementwise
            for (int c = 0; c < N_NODES / CH; c++) {
                int c0 = c * CH;
                dim3 grid((CH + 127) / 128, 1024 / 128);
                mm_bf16<<<grid, 256, 0, stream>>>(msgs + (size_t)c0 * H, 256, 256,
                                                  h + (size_t)c0 * H,
                                                  BC, 512, Cb, nullptr, 0,
                                                  scr, 1024, CH);
                gru_kernel<<<CH, 256, 0, stream>>>(h, scr, c0, CH);
            }
        }
    }

    gate_kernel<<<(N_NODES * 64) / 256, 256, 0, stream>>>(h, gate_W, gate_b, g);
    out_kernel<<<N_GRAPHS, 256, 0, stream>>>(h, g, gsizes, out_W, out_b, out);
}

// Round 8
// 3470.696 us; speedup vs baseline: 7.2652x; 1.1594x over previous
//
#include <hip/hip_runtime.h>
#include <math.h>

#define N_NODES 100000
#define N_GRAPHS 100
#define N_EDGES 1000000
#define H 256
#define L_POS 512
#define CH 20000        // node chunk (5 chunks)
#define NCH (N_NODES / CH)
#define NBUCK (4 * N_NODES)
#define NBLK ((NBUCK + 255) / 256)

typedef short bf16x8 __attribute__((ext_vector_type(8)));
typedef float f32x4  __attribute__((ext_vector_type(4)));

__device__ inline short f2bf(float f) {
    union { float f; unsigned u; } v; v.f = f;
    unsigned r = (v.u + 0x7FFF + ((v.u >> 16) & 1)) >> 16;
    return (short)r;
}
__device__ inline float bf2f(unsigned short u) {
    union { unsigned u; float f; } v; v.u = ((unsigned)u) << 16;
    return v.f;
}

// ---------------- zero ints ----------------
__global__ void zero_int(int4* __restrict__ p, int n4)
{
    int i = blockIdx.x * 256 + threadIdx.x;
    if (i < n4) p[i] = make_int4(0, 0, 0, 0);
}

// ---------------- init h (bf16) ----------------
__global__ void init_h_kernel(const int* __restrict__ nodes,
                              const float* __restrict__ embed,
                              short* __restrict__ h)
{
    int n = blockIdx.x;
    int j = threadIdx.x;
    int tok = nodes[n];
    int p = nodes[N_NODES + n];
    if (p > L_POS) p = L_POS;
    float pe = 0.0f;
    if (p > 0) {
        float pos = (float)(p - 1);
        float denom = powf(10000.0f, 2.0f * (float)j / (float)H);
        float ang = pos / denom;
        pe = (j & 1) ? cosf(ang) : sinf(ang);
    }
    h[(size_t)n * H + j] = f2bf(embed[(size_t)tok * H + j] + pe);
}

// ---------------- weight prep ----------------
// Wstack BT layout: [l][n][k=1024], k = t*256+kk: BT = type_w[l][t][kk][n]
__global__ void cvt_wstack(const float* __restrict__ w, short* __restrict__ wt)
{
    int idx = blockIdx.x * 256 + threadIdx.x;
    if (idx >= 2 * 256 * 1024) return;
    int l = idx / (256 * 1024);
    int rem = idx % (256 * 1024);
    int n = rem >> 10, k = rem & 1023;
    int t = k >> 8, kk = k & 255;
    wt[idx] = f2bf(w[(((size_t)(l * 4 + t)) * 256 + kk) * 256 + n]);
}
// Bcomb[l][n][k512]: [msgs|h] @ Bcomb = [S_z|S_r|S_xh|hh]
__global__ void cvt_comb(const float* __restrict__ W, const float* __restrict__ U,
                         short* __restrict__ B)
{
    int idx = blockIdx.x * 256 + threadIdx.x;
    if (idx >= 2 * 1024 * 512) return;
    int l = idx / (1024 * 512);
    int rem = idx % (1024 * 512);
    int n = rem >> 9, k = rem & 511;
    float v = 0.0f;
    if (n < 512) {
        v = (k < 256) ? W[((size_t)l * 256 + k) * 768 + n]
                      : U[((size_t)l * 256 + (k - 256)) * 768 + n];
    } else if (n < 768) {
        if (k < 256) v = W[((size_t)l * 256 + k) * 768 + n];
    } else {
        if (k >= 256) v = U[((size_t)l * 256 + (k - 256)) * 768 + (n - 256)];
    }
    B[idx] = f2bf(v);
}
__global__ void cvt_bias(const float* __restrict__ bi, const float* __restrict__ br,
                         float* __restrict__ biasC)
{
    int idx = blockIdx.x * 256 + threadIdx.x;
    if (idx >= 2048) return;
    int l = idx >> 10, n = idx & 1023;
    float v;
    if (n < 512)      v = bi[l * 768 + n] + br[l * 768 + n];
    else if (n < 768) v = bi[l * 768 + n];
    else              v = br[l * 768 + (n - 256)];
    biasC[idx] = v;
}

// ---------------- CSR build: bucket = etype*N_NODES + tgt ----------------
__global__ void histo_kernel(const int* __restrict__ edges, int* __restrict__ counts)
{
    int e = blockIdx.x * 256 + threadIdx.x;
    if (e >= N_EDGES) return;
    int t = edges[e * 3];
    int tg = edges[e * 3 + 2];
    atomicAdd(&counts[t * N_NODES + tg], 1);
}
__global__ void scan1(const int* __restrict__ counts, int* __restrict__ partial)
{
    __shared__ int s[256];
    int i = blockIdx.x * 256 + threadIdx.x;
    s[threadIdx.x] = (i < NBUCK) ? counts[i] : 0;
    __syncthreads();
    for (int off = 128; off > 0; off >>= 1) {
        if (threadIdx.x < off) s[threadIdx.x] += s[threadIdx.x + off];
        __syncthreads();
    }
    if (threadIdx.x == 0) partial[blockIdx.x] = s[0];
}
__global__ void scan2(int* __restrict__ partial, int* __restrict__ offs)
{
    if (threadIdx.x == 0 && blockIdx.x == 0) {
        int run = 0;
        for (int i = 0; i < NBLK; i++) { int v = partial[i]; partial[i] = run; run += v; }
        offs[NBUCK] = run;
    }
}
__global__ void scan3(const int* __restrict__ counts, const int* __restrict__ partial,
                      int* __restrict__ offs)
{
    __shared__ int s[256];
    int i = blockIdx.x * 256 + threadIdx.x;
    int v = (i < NBUCK) ? counts[i] : 0;
    s[threadIdx.x] = v;
    __syncthreads();
    for (int off = 1; off < 256; off <<= 1) {
        int add = (threadIdx.x >= off) ? s[threadIdx.x - off] : 0;
        __syncthreads();
        s[threadIdx.x] += add;
        __syncthreads();
    }
    if (i < NBUCK) offs[i] = partial[blockIdx.x] + s[threadIdx.x] - v;
}
__global__ void fill_kernel(const int* __restrict__ edges, const int* __restrict__ offs,
                            int* __restrict__ cursors, int* __restrict__ srcs)
{
    int e = blockIdx.x * 256 + threadIdx.x;
    if (e >= N_EDGES) return;
    int t = edges[e * 3];
    int s = edges[e * 3 + 1];
    int tg = edges[e * 3 + 2];
    int b = t * N_NODES + tg;
    int p = atomicAdd(&cursors[b], 1);
    srcs[offs[b] + p] = s;
}

// ---- gather (bf16 h): gath4[tgt-c0][t*256+col] = bf16( sum_e h[src][col] ) ----
__global__ __launch_bounds__(256) void gather_kernel(
    const int* __restrict__ offs, const int* __restrict__ srcs,
    const short* __restrict__ h, short* __restrict__ gath4, int c0)
{
    int w = (blockIdx.x * 256 + threadIdx.x) >> 6;
    int lane = threadIdx.x & 63;
    if (w >= CH) return;
    int tgt = c0 + w;
    int col = lane * 4;
    #pragma unroll
    for (int t = 0; t < 4; t++) {
        int b = t * N_NODES + tgt;
        int e0 = offs[b], e1 = offs[b + 1];
        float4 acc = make_float4(0.f, 0.f, 0.f, 0.f);
        for (int e = e0; e < e1; e++) {
            int src = srcs[e];
            uint2 pk = *(const uint2*)(h + (size_t)src * H + col);
            acc.x += bf2f((unsigned short)(pk.x & 0xFFFF));
            acc.y += bf2f((unsigned short)(pk.x >> 16));
            acc.z += bf2f((unsigned short)(pk.y & 0xFFFF));
            acc.w += bf2f((unsigned short)(pk.y >> 16));
        }
        unsigned p0 = ((unsigned)(unsigned short)f2bf(acc.x)) |
                      (((unsigned)(unsigned short)f2bf(acc.y)) << 16);
        unsigned p1 = ((unsigned)(unsigned short)f2bf(acc.z)) |
                      (((unsigned)(unsigned short)f2bf(acc.w)) << 16);
        *(uint2*)(gath4 + (size_t)w * 1024 + t * 256 + col) = make_uint2(p0, p1);
    }
}

// ---- bf16 MFMA matmul: C(nrows x gridDim.y*128, bf16) = [A0 | A1] @ BT^T + bias
// A0: bf16 stride s0, k < K0. A1: bf16 stride s1, k >= K0.
// cnt != null: bias = Sum_t cnt[t*N + c0 + row] * bias[t*256 + col]
__global__ __launch_bounds__(256) void mm_bf16(
    const short* __restrict__ A0, int s0, const short* __restrict__ A1, int s1, int K0,
    const short* __restrict__ BT, int Ktot,
    const float* __restrict__ bias,
    const int* __restrict__ cnt, int c0,
    short* __restrict__ C, int ldc, int nrows)
{
    __shared__ short As[128 * 40];
    __shared__ short Bs[128 * 40];
    const int tid = threadIdx.x;
    const int bm = blockIdx.x * 128;
    const int bn = blockIdx.y * 128;
    const int lane = tid & 63;
    const int wave = tid >> 6;
    const int wm = (wave >> 1) * 64;
    const int wn = (wave & 1) * 64;
    const int q = lane >> 4;
    const int r16 = lane & 15;

    f32x4 acc[4][4];
    #pragma unroll
    for (int i = 0; i < 4; i++)
        #pragma unroll
        for (int j = 0; j < 4; j++)
            acc[i][j] = (f32x4){0.f, 0.f, 0.f, 0.f};

    const int srow = tid >> 1;
    const int skh  = (tid & 1) * 16;
    const int agr  = bm + srow;
    const bool aok = agr < nrows;
    const short* Bp = BT + (size_t)(bn + srow) * Ktot + skh;

    for (int k0 = 0; k0 < Ktot; k0 += 32) {
        uint4 av0, av1;
        if (!aok) {
            av0 = make_uint4(0, 0, 0, 0); av1 = make_uint4(0, 0, 0, 0);
        } else {
            const short* Ap = (k0 < K0)
                ? A0 + (size_t)agr * s0 + k0 + skh
                : A1 + (size_t)agr * s1 + (k0 - K0) + skh;
            av0 = *(const uint4*)Ap;
            av1 = *(const uint4*)(Ap + 8);
        }
        uint4 b0 = *(const uint4*)(Bp + k0);
        uint4 b1 = *(const uint4*)(Bp + k0 + 8);

        __syncthreads();
        *(uint4*)&As[srow * 40 + skh]     = av0;
        *(uint4*)&As[srow * 40 + skh + 8] = av1;
        *(uint4*)&Bs[srow * 40 + skh]     = b0;
        *(uint4*)&Bs[srow * 40 + skh + 8] = b1;
        __syncthreads();

        bf16x8 af[4], bfr[4];
        #pragma unroll
        for (int mt = 0; mt < 4; mt++)
            af[mt] = *(const bf16x8*)&As[(wm + mt * 16 + r16) * 40 + q * 8];
        #pragma unroll
        for (int nt = 0; nt < 4; nt++)
            bfr[nt] = *(const bf16x8*)&Bs[(wn + nt * 16 + r16) * 40 + q * 8];
        #pragma unroll
        for (int mt = 0; mt < 4; mt++)
            #pragma unroll
            for (int nt = 0; nt < 4; nt++)
                acc[mt][nt] = __builtin_amdgcn_mfma_f32_16x16x32_bf16(af[mt], bfr[nt], acc[mt][nt], 0, 0, 0);
    }

    #pragma unroll
    for (int mt = 0; mt < 4; mt++) {
        #pragma unroll
        for (int reg = 0; reg < 4; reg++) {
            int row = bm + wm + mt * 16 + q * 4 + reg;
            if (row >= nrows) continue;
            #pragma unroll
            for (int nt = 0; nt < 4; nt++) {
                int col = bn + wn + nt * 16 + r16;
                float v = acc[mt][nt][reg];
                if (cnt) {
                    #pragma unroll
                    for (int t = 0; t < 4; t++)
                        v += (float)cnt[t * N_NODES + c0 + row] * bias[t * 256 + col];
                } else {
                    v += bias[col];
                }
                C[(size_t)row * ldc + col] = f2bf(v);
            }
        }
    }
}

// ---- GRU elementwise: S rows [z|r|xh|hh] (1024, bf16); hOld -> hNew (bf16) ----
__global__ void gru_kernel(const short* __restrict__ hOld, short* __restrict__ hNew,
                           const short* __restrict__ S, int r0)
{
    int nl = blockIdx.x;
    int j = threadIdx.x;
    int n = r0 + nl;
    const short* Srow = S + (size_t)nl * 1024;
    float sz = bf2f((unsigned short)Srow[j]);
    float sr = bf2f((unsigned short)Srow[256 + j]);
    float xh = bf2f((unsigned short)Srow[512 + j]);
    float hh = bf2f((unsigned short)Srow[768 + j]);
    size_t idx = (size_t)n * H + j;
    float hv = bf2f((unsigned short)hOld[idx]);
    float z = 1.0f / (1.0f + expf(-sz));
    float r = 1.0f / (1.0f + expf(-sr));
    float cand = tanhf(xh + r * hh);
    hNew[idx] = f2bf(z * hv + (1.0f - z) * cand);
}

// ---------------- gate logits (bf16 h) ----------------
__global__ __launch_bounds__(256) void gate_kernel(const short* __restrict__ h,
                                                   const float* __restrict__ gW,
                                                   const float* __restrict__ gb,
                                                   float* __restrict__ g)
{
    int tid = blockIdx.x * 256 + threadIdx.x;
    int n = tid >> 6;
    if (n >= N_NODES) return;
    int lane = tid & 63;
    uint2 pk = *(const uint2*)(h + (size_t)n * H + lane * 4);
    float4 w = *(const float4*)(gW + lane * 4);
    float s = bf2f((unsigned short)(pk.x & 0xFFFF)) * w.x
            + bf2f((unsigned short)(pk.x >> 16))    * w.y
            + bf2f((unsigned short)(pk.y & 0xFFFF)) * w.z
            + bf2f((unsigned short)(pk.y >> 16))    * w.w;
    #pragma unroll
    for (int off = 32; off > 0; off >>= 1)
        s += __shfl_down(s, off);
    if (lane == 0) g[n] = s + gb[0];
}

// ---------------- per-graph softmax-gated readout (parallel phase 3) ----------------
__global__ __launch_bounds__(256) void out_kernel(const short* __restrict__ h,
                                                  const float* __restrict__ g,
                                                  const int* __restrict__ sizes,
                                                  const float* __restrict__ outW,
                                                  const float* __restrict__ outB,
                                                  float* __restrict__ out)
{
    __shared__ float red[256];
    __shared__ float red4[4][256];
    int gid = blockIdx.x;
    int tid = threadIdx.x;
    int wave = tid >> 6;
    int lane = tid & 63;

    int start = 0, end = 0;
    {
        int c = 0;
        for (int i = 0; i < N_GRAPHS; i++) {
            int sz = sizes[i];
            if (i == gid) { start = c; end = c + sz; }
            c += sz;
        }
    }

    float m = -INFINITY;
    for (int n = start + tid; n < end; n += 256) m = fmaxf(m, g[n]);
    red[tid] = m; __syncthreads();
    for (int s = 128; s > 0; s >>= 1) {
        if (tid < s) red[tid] = fmaxf(red[tid], red[tid + s]);
        __syncthreads();
    }
    m = red[0]; __syncthreads();

    float s_ = 0.0f;
    for (int n = start + tid; n < end; n += 256) s_ += expf(g[n] - m);
    red[tid] = s_; __syncthreads();
    for (int s = 128; s > 0; s >>= 1) {
        if (tid < s) red[tid] += red[tid + s];
        __syncthreads();
    }
    float ssum = red[0]; __syncthreads();

    // phase 3: 4 waves split nodes; lane covers cols lane*4..lane*4+3
    float a0 = 0.f, a1 = 0.f, a2 = 0.f, a3 = 0.f;
    for (int n = start + wave; n < end; n += 4) {
        float e = expf(g[n] - m);
        uint2 pk = *(const uint2*)(h + (size_t)n * H + lane * 4);
        a0 += e * bf2f((unsigned short)(pk.x & 0xFFFF));
        a1 += e * bf2f((unsigned short)(pk.x >> 16));
        a2 += e * bf2f((unsigned short)(pk.y & 0xFFFF));
        a3 += e * bf2f((unsigned short)(pk.y >> 16));
    }
    red4[wave][lane * 4 + 0] = a0;
    red4[wave][lane * 4 + 1] = a1;
    red4[wave][lane * 4 + 2] = a2;
    red4[wave][lane * 4 + 3] = a3;
    __syncthreads();
    float acc = red4[0][tid] + red4[1][tid] + red4[2][tid] + red4[3][tid];
    __syncthreads();

    float inv = 1.0f / (ssum + 1e-16f);
    for (int c = 0; c < 2; c++) {
        red[tid] = acc * outW[tid * 2 + c];
        __syncthreads();
        for (int s = 128; s > 0; s >>= 1) {
            if (tid < s) red[tid] += red[tid + s];
            __syncthreads();
        }
        if (tid == 0) out[gid * 2 + c] = red[0] * inv + outB[c] * (ssum * inv);
        __syncthreads();
    }
}

static inline size_t alup(size_t x) { return (x + 255) & ~(size_t)255; }

extern "C" void kernel_launch(void* const* d_in, const int* in_sizes, int n_in,
                              void* d_out, int out_size, void* d_ws, size_t ws_size,
                              hipStream_t stream)
{
    const int*   nodes  = (const int*)d_in[0];
    const int*   gsizes = (const int*)d_in[1];
    const int*   edges  = (const int*)d_in[2];
    const float* embed  = (const float*)d_in[3];
    const float* type_w = (const float*)d_in[4];
    const float* type_b = (const float*)d_in[5];
    const float* gru_W  = (const float*)d_in[6];
    const float* gru_U  = (const float*)d_in[7];
    const float* gru_bi = (const float*)d_in[8];
    const float* gru_br = (const float*)d_in[9];
    const float* gate_W = (const float*)d_in[10];
    const float* gate_b = (const float*)d_in[11];
    const float* out_W  = (const float*)d_in[12];
    const float* out_b  = (const float*)d_in[13];
    float* out = (float*)d_out;

    // ---- workspace layout (bytes), total ~166 MB ----
    const size_t SZ_HB   = alup((size_t)N_NODES * H * 2);      // 51.2 MB bf16 (x2 buffers)
    const size_t SZ_SCR1 = alup((size_t)CH * 1024 * 2);        // 40.96 MB (gath4 / S)
    const size_t SZ_SCR2 = alup((size_t)CH * 256 * 2);         // 10.24 MB (msgs chunk)
    const size_t SZ_G    = alup((size_t)N_NODES * 4);
    const size_t SZ_WST  = alup((size_t)2 * 256 * 1024 * 2);
    const size_t SZ_BC   = alup((size_t)2 * 1024 * 512 * 2);
    const size_t SZ_BIAS = alup((size_t)2 * 1024 * 4);
    const size_t SZ_CNT  = alup((size_t)NBUCK * 4);
    const size_t SZ_CUR  = SZ_CNT;
    const size_t SZ_OFF  = alup((size_t)(NBUCK + 1) * 4);
    const size_t SZ_SRC  = alup((size_t)N_EDGES * 4);
    const size_t SZ_PART = alup((size_t)NBLK * 4);
    size_t need = 2 * SZ_HB + SZ_SCR1 + SZ_SCR2 + SZ_G + SZ_WST + SZ_BC + SZ_BIAS +
                  SZ_CNT + SZ_CUR + SZ_OFF + SZ_SRC + SZ_PART;
    if (ws_size < need) return;

    char* base = (char*)d_ws;
    short* hA     = (short*)base;  base += SZ_HB;
    short* hB     = (short*)base;  base += SZ_HB;
    short* scr1   = (short*)base;  base += SZ_SCR1;  // gath4 / S
    short* scr2   = (short*)base;  base += SZ_SCR2;  // msgs chunk
    float* g      = (float*)base;  base += SZ_G;
    short* Wstack = (short*)base;  base += SZ_WST;
    short* Bcomb  = (short*)base;  base += SZ_BC;
    float* biasC  = (float*)base;  base += SZ_BIAS;
    int*   counts = (int*)base;    base += SZ_CNT;
    int*   cursors= (int*)base;    base += SZ_CUR;
    int*   offs   = (int*)base;    base += SZ_OFF;
    int*   srcs   = (int*)base;    base += SZ_SRC;
    int*   partial= (int*)base;    base += SZ_PART;

    // ---- prep ----
    cvt_wstack<<<(2 * 256 * 1024) / 256, 256, 0, stream>>>(type_w, Wstack);
    cvt_comb<<<(2 * 1024 * 512) / 256, 256, 0, stream>>>(gru_W, gru_U, Bcomb);
    cvt_bias<<<8, 256, 0, stream>>>(gru_bi, gru_br, biasC);
    {
        int n4 = (int)((SZ_CNT + SZ_CUR) / 16);
        zero_int<<<(n4 + 255) / 256, 256, 0, stream>>>((int4*)counts, n4);
    }
    histo_kernel<<<(N_EDGES + 255) / 256, 256, 0, stream>>>(edges, counts);
    scan1<<<NBLK, 256, 0, stream>>>(counts, partial);
    scan2<<<1, 64, 0, stream>>>(partial, offs);
    scan3<<<NBLK, 256, 0, stream>>>(counts, partial, offs);
    fill_kernel<<<(N_EDGES + 255) / 256, 256, 0, stream>>>(edges, offs, cursors, srcs);
    init_h_kernel<<<N_NODES, H, 0, stream>>>(nodes, embed, hA);

    short* cur = hA;
    short* nxt = hB;
    const int steps[2] = {3, 1};
    for (int l = 0; l < 2; l++) {
        const short* WS = Wstack + (size_t)l * 256 * 1024;
        const float* Tb = type_b + (size_t)l * 4 * 256;
        const short* BC = Bcomb + (size_t)l * 1024 * 512;
        const float* Cb = biasC + (size_t)l * 1024;
        for (int s = 0; s < steps[l]; s++) {
            for (int c = 0; c < NCH; c++) {
                int c0 = c * CH;
                gather_kernel<<<CH / 4, 256, 0, stream>>>(offs, srcs, cur, scr1, c0);
                dim3 g1((CH + 127) / 128, 256 / 128);
                mm_bf16<<<g1, 256, 0, stream>>>(scr1, 1024, nullptr, 0, 1024,
                                                WS, 1024, Tb, counts, c0,
                                                scr2, 256, CH);
                dim3 g2((CH + 127) / 128, 1024 / 128);
                mm_bf16<<<g2, 256, 0, stream>>>(scr2, 256, cur + (size_t)c0 * H, 256, 256,
                                                BC, 512, Cb, nullptr, 0,
                                                scr1, 1024, CH);
                gru_kernel<<<CH, 256, 0, stream>>>(cur, nxt, scr1, c0);
            }
            short* t = cur; cur = nxt; nxt = t;
        }
    }

    gate_kernel<<<(N_NODES * 64) / 256, 256, 0, stream>>>(cur, gate_W, gate_b, g);
    out_kernel<<<N_GRAPHS, 256, 0, stream>>>(cur, g, gsizes, out_W, out_b, out);
}

// Round 9
// 2954.847 us; speedup vs baseline: 8.5335x; 1.1746x over previous
//
#include <hip/hip_runtime.h>
#include <math.h>

#define N_NODES 100000
#define N_GRAPHS 100
#define N_EDGES 1000000
#define H 256
#define L_POS 512
#define NBUCK (4 * N_NODES)
#define NBLK ((NBUCK + 255) / 256)

typedef short bf16x8 __attribute__((ext_vector_type(8)));
typedef float f32x4  __attribute__((ext_vector_type(4)));

__device__ inline short f2bf(float f) {
    union { float f; unsigned u; } v; v.f = f;
    unsigned r = (v.u + 0x7FFF + ((v.u >> 16) & 1)) >> 16;
    return (short)r;
}
__device__ inline float bf2f(unsigned short u) {
    union { unsigned u; float f; } v; v.u = ((unsigned)u) << 16;
    return v.f;
}

// ---------------- zero ints ----------------
__global__ void zero_int(int4* __restrict__ p, int n4)
{
    int i = blockIdx.x * 256 + threadIdx.x;
    if (i < n4) p[i] = make_int4(0, 0, 0, 0);
}

// ---------------- PE table: pe[p][j], p in [0,512] ----------------
__global__ void pe_kernel(float* __restrict__ pe)
{
    int p = blockIdx.x;      // 0..512
    int j = threadIdx.x;     // 0..255
    float v = 0.0f;
    if (p > 0) {
        float pos = (float)(p - 1);
        float denom = powf(10000.0f, 2.0f * (float)j / (float)H);
        float ang = pos / denom;
        v = (j & 1) ? cosf(ang) : sinf(ang);
    }
    pe[p * H + j] = v;
}

// ---------------- init h (bf16): h = embed[tok] + pe_tab[min(pos,512)] ----------------
__global__ void init_h_kernel(const int* __restrict__ nodes,
                              const float* __restrict__ embed,
                              const float* __restrict__ pe,
                              short* __restrict__ h)
{
    int n = blockIdx.x;
    int j = threadIdx.x;
    int tok = nodes[n];
    int p = nodes[N_NODES + n];
    if (p > L_POS) p = L_POS;
    h[(size_t)n * H + j] = f2bf(embed[(size_t)tok * H + j] + pe[p * H + j]);
}

// ---------------- weight prep ----------------
__global__ void cvt_wstack(const float* __restrict__ w, short* __restrict__ wt)
{
    int idx = blockIdx.x * 256 + threadIdx.x;
    if (idx >= 2 * 256 * 1024) return;
    int l = idx / (256 * 1024);
    int rem = idx % (256 * 1024);
    int n = rem >> 10, k = rem & 1023;
    int t = k >> 8, kk = k & 255;
    wt[idx] = f2bf(w[(((size_t)(l * 4 + t)) * 256 + kk) * 256 + n]);
}
__global__ void cvt_comb(const float* __restrict__ W, const float* __restrict__ U,
                         short* __restrict__ B)
{
    int idx = blockIdx.x * 256 + threadIdx.x;
    if (idx >= 2 * 1024 * 512) return;
    int l = idx / (1024 * 512);
    int rem = idx % (1024 * 512);
    int n = rem >> 9, k = rem & 511;
    float v = 0.0f;
    if (n < 512) {
        v = (k < 256) ? W[((size_t)l * 256 + k) * 768 + n]
                      : U[((size_t)l * 256 + (k - 256)) * 768 + n];
    } else if (n < 768) {
        if (k < 256) v = W[((size_t)l * 256 + k) * 768 + n];
    } else {
        if (k >= 256) v = U[((size_t)l * 256 + (k - 256)) * 768 + (n - 256)];
    }
    B[idx] = f2bf(v);
}
__global__ void cvt_bias(const float* __restrict__ bi, const float* __restrict__ br,
                         float* __restrict__ biasC)
{
    int idx = blockIdx.x * 256 + threadIdx.x;
    if (idx >= 2048) return;
    int l = idx >> 10, n = idx & 1023;
    float v;
    if (n < 512)      v = bi[l * 768 + n] + br[l * 768 + n];
    else if (n < 768) v = bi[l * 768 + n];
    else              v = br[l * 768 + (n - 256)];
    biasC[idx] = v;
}

// ---------------- CSR build: bucket = etype*N_NODES + tgt ----------------
__global__ void histo_kernel(const int* __restrict__ edges, int* __restrict__ counts)
{
    int e = blockIdx.x * 256 + threadIdx.x;
    if (e >= N_EDGES) return;
    int t = edges[e * 3];
    int tg = edges[e * 3 + 2];
    atomicAdd(&counts[t * N_NODES + tg], 1);
}
__global__ void scan1(const int* __restrict__ counts, int* __restrict__ partial)
{
    __shared__ int s[256];
    int i = blockIdx.x * 256 + threadIdx.x;
    s[threadIdx.x] = (i < NBUCK) ? counts[i] : 0;
    __syncthreads();
    for (int off = 128; off > 0; off >>= 1) {
        if (threadIdx.x < off) s[threadIdx.x] += s[threadIdx.x + off];
        __syncthreads();
    }
    if (threadIdx.x == 0) partial[blockIdx.x] = s[0];
}
__global__ void scan2(int* __restrict__ partial, int* __restrict__ offs)
{
    if (threadIdx.x == 0 && blockIdx.x == 0) {
        int run = 0;
        for (int i = 0; i < NBLK; i++) { int v = partial[i]; partial[i] = run; run += v; }
        offs[NBUCK] = run;
    }
}
__global__ void scan3(const int* __restrict__ counts, const int* __restrict__ partial,
                      int* __restrict__ offs)
{
    __shared__ int s[256];
    int i = blockIdx.x * 256 + threadIdx.x;
    int v = (i < NBUCK) ? counts[i] : 0;
    s[threadIdx.x] = v;
    __syncthreads();
    for (int off = 1; off < 256; off <<= 1) {
        int add = (threadIdx.x >= off) ? s[threadIdx.x - off] : 0;
        __syncthreads();
        s[threadIdx.x] += add;
        __syncthreads();
    }
    if (i < NBUCK) offs[i] = partial[blockIdx.x] + s[threadIdx.x] - v;
}
__global__ void fill_kernel(const int* __restrict__ edges, const int* __restrict__ offs,
                            int* __restrict__ cursors, int* __restrict__ srcs)
{
    int e = blockIdx.x * 256 + threadIdx.x;
    if (e >= N_EDGES) return;
    int t = edges[e * 3];
    int s = edges[e * 3 + 1];
    int tg = edges[e * 3 + 2];
    int b = t * N_NODES + tg;
    int p = atomicAdd(&cursors[b], 1);
    srcs[offs[b] + p] = s;
}

// ---- gather (bf16 h): gath4[tgt-c0][t*256+col] = bf16( sum_e h[src][col] ) ----
__global__ __launch_bounds__(256) void gather_kernel(
    const int* __restrict__ offs, const int* __restrict__ srcs,
    const short* __restrict__ h, short* __restrict__ gath4, int c0, int nr)
{
    int w = (blockIdx.x * 256 + threadIdx.x) >> 6;
    int lane = threadIdx.x & 63;
    if (w >= nr) return;
    int tgt = c0 + w;
    int col = lane * 4;
    #pragma unroll
    for (int t = 0; t < 4; t++) {
        int b = t * N_NODES + tgt;
        int e0 = offs[b], e1 = offs[b + 1];
        float4 acc = make_float4(0.f, 0.f, 0.f, 0.f);
        for (int e = e0; e < e1; e++) {
            int src = srcs[e];
            uint2 pk = *(const uint2*)(h + (size_t)src * H + col);
            acc.x += bf2f((unsigned short)(pk.x & 0xFFFF));
            acc.y += bf2f((unsigned short)(pk.x >> 16));
            acc.z += bf2f((unsigned short)(pk.y & 0xFFFF));
            acc.w += bf2f((unsigned short)(pk.y >> 16));
        }
        unsigned p0 = ((unsigned)(unsigned short)f2bf(acc.x)) |
                      (((unsigned)(unsigned short)f2bf(acc.y)) << 16);
        unsigned p1 = ((unsigned)(unsigned short)f2bf(acc.z)) |
                      (((unsigned)(unsigned short)f2bf(acc.w)) << 16);
        *(uint2*)(gath4 + (size_t)w * 1024 + t * 256 + col) = make_uint2(p0, p1);
    }
}

// ---- bf16 MFMA matmul with register prefetch across the barrier ----
// C(nrows x gridDim.y*128, bf16) = [A0 | A1] @ BT^T + bias
// A0: bf16 stride s0 (k < K0); A1: bf16 stride s1 (k >= K0). BT: bf16 [n][Ktot].
// cnt != null: bias = Sum_t cnt[t*N + c0 + row] * bias[t*256 + col]
__global__ __launch_bounds__(256) void mm_bf16(
    const short* __restrict__ A0, int s0, const short* __restrict__ A1, int s1, int K0,
    const short* __restrict__ BT, int Ktot,
    const float* __restrict__ bias,
    const int* __restrict__ cnt, int c0,
    short* __restrict__ C, int ldc, int nrows)
{
    __shared__ short As[128 * 40];
    __shared__ short Bs[128 * 40];
    const int tid = threadIdx.x;
    const int bm = blockIdx.x * 128;
    const int bn = blockIdx.y * 128;
    const int lane = tid & 63;
    const int wave = tid >> 6;
    const int wm = (wave >> 1) * 64;
    const int wn = (wave & 1) * 64;
    const int q = lane >> 4;
    const int r16 = lane & 15;

    f32x4 acc[4][4];
    #pragma unroll
    for (int i = 0; i < 4; i++)
        #pragma unroll
        for (int j = 0; j < 4; j++)
            acc[i][j] = (f32x4){0.f, 0.f, 0.f, 0.f};

    const int srow = tid >> 1;
    const int skh  = (tid & 1) * 16;
    const int agr  = bm + srow;
    const bool aok = agr < nrows;
    const short* Bp = BT + (size_t)(bn + srow) * Ktot + skh;

    // prologue: load tile k0=0
    uint4 av0, av1, bv0, bv1;
    {
        if (aok) {
            const short* Ap = (0 + skh < K0 || K0 == 0)
                ? A0 + (size_t)agr * s0 + skh
                : A1 + (size_t)agr * s1 + (skh - K0);
            // skh in {0,16}: tile 0 always entirely in A0 when K0>=32 (true here)
            av0 = *(const uint4*)Ap;
            av1 = *(const uint4*)(Ap + 8);
        } else { av0 = make_uint4(0,0,0,0); av1 = make_uint4(0,0,0,0); }
        bv0 = *(const uint4*)Bp;
        bv1 = *(const uint4*)(Bp + 8);
    }

    for (int k0 = 0; k0 < Ktot; k0 += 32) {
        __syncthreads();
        *(uint4*)&As[srow * 40 + skh]     = av0;
        *(uint4*)&As[srow * 40 + skh + 8] = av1;
        *(uint4*)&Bs[srow * 40 + skh]     = bv0;
        *(uint4*)&Bs[srow * 40 + skh + 8] = bv1;
        __syncthreads();

        // prefetch next tile BEFORE the MFMA section (latency hidden by MFMA)
        int kn = k0 + 32;
        if (kn < Ktot) {
            if (aok) {
                int kk = kn + skh;
                const short* Ap = (kk < K0)
                    ? A0 + (size_t)agr * s0 + kk
                    : A1 + (size_t)agr * s1 + (kk - K0);
                av0 = *(const uint4*)Ap;
                av1 = *(const uint4*)(Ap + 8);
            }
            bv0 = *(const uint4*)(Bp + kn);
            bv1 = *(const uint4*)(Bp + kn + 8);
        }

        bf16x8 af[4], bfr[4];
        #pragma unroll
        for (int mt = 0; mt < 4; mt++)
            af[mt] = *(const bf16x8*)&As[(wm + mt * 16 + r16) * 40 + q * 8];
        #pragma unroll
        for (int nt = 0; nt < 4; nt++)
            bfr[nt] = *(const bf16x8*)&Bs[(wn + nt * 16 + r16) * 40 + q * 8];
        #pragma unroll
        for (int mt = 0; mt < 4; mt++)
            #pragma unroll
            for (int nt = 0; nt < 4; nt++)
                acc[mt][nt] = __builtin_amdgcn_mfma_f32_16x16x32_bf16(af[mt], bfr[nt], acc[mt][nt], 0, 0, 0);
    }

    #pragma unroll
    for (int mt = 0; mt < 4; mt++) {
        #pragma unroll
        for (int reg = 0; reg < 4; reg++) {
            int row = bm + wm + mt * 16 + q * 4 + reg;
            if (row >= nrows) continue;
            #pragma unroll
            for (int nt = 0; nt < 4; nt++) {
                int col = bn + wn + nt * 16 + r16;
                float v = acc[mt][nt][reg];
                if (cnt) {
                    #pragma unroll
                    for (int t = 0; t < 4; t++)
                        v += (float)cnt[t * N_NODES + c0 + row] * bias[t * 256 + col];
                } else {
                    v += bias[col];
                }
                C[(size_t)row * ldc + col] = f2bf(v);
            }
        }
    }
}

// ---- GRU elementwise (vectorized): S rows [z|r|xh|hh] (1024, bf16); hOld -> hNew ----
__global__ __launch_bounds__(256) void gru_kernel(const short* __restrict__ hOld,
                                                  short* __restrict__ hNew,
                                                  const short* __restrict__ S,
                                                  int r0, int nr)
{
    int t = blockIdx.x * 256 + threadIdx.x;
    int nl = t >> 6;
    if (nl >= nr) return;
    int lane = t & 63;
    const short* Srow = S + (size_t)nl * 1024 + lane * 4;
    uint2 pz = *(const uint2*)(Srow);
    uint2 pr = *(const uint2*)(Srow + 256);
    uint2 px = *(const uint2*)(Srow + 512);
    uint2 ph = *(const uint2*)(Srow + 768);
    size_t idx = (size_t)(r0 + nl) * H + lane * 4;
    uint2 po = *(const uint2*)(hOld + idx);

    float outv[4];
    unsigned zs[4] = { pz.x & 0xFFFF, pz.x >> 16, pz.y & 0xFFFF, pz.y >> 16 };
    unsigned rs[4] = { pr.x & 0xFFFF, pr.x >> 16, pr.y & 0xFFFF, pr.y >> 16 };
    unsigned xs[4] = { px.x & 0xFFFF, px.x >> 16, px.y & 0xFFFF, px.y >> 16 };
    unsigned hs[4] = { ph.x & 0xFFFF, ph.x >> 16, ph.y & 0xFFFF, ph.y >> 16 };
    unsigned os[4] = { po.x & 0xFFFF, po.x >> 16, po.y & 0xFFFF, po.y >> 16 };
    #pragma unroll
    for (int i = 0; i < 4; i++) {
        float z = 1.0f / (1.0f + expf(-bf2f((unsigned short)zs[i])));
        float r = 1.0f / (1.0f + expf(-bf2f((unsigned short)rs[i])));
        float cand = tanhf(bf2f((unsigned short)xs[i]) + r * bf2f((unsigned short)hs[i]));
        outv[i] = z * bf2f((unsigned short)os[i]) + (1.0f - z) * cand;
    }
    unsigned w0 = ((unsigned)(unsigned short)f2bf(outv[0])) |
                  (((unsigned)(unsigned short)f2bf(outv[1])) << 16);
    unsigned w1 = ((unsigned)(unsigned short)f2bf(outv[2])) |
                  (((unsigned)(unsigned short)f2bf(outv[3])) << 16);
    *(uint2*)(hNew + idx) = make_uint2(w0, w1);
}

// ---------------- gate logits (bf16 h) ----------------
__global__ __launch_bounds__(256) void gate_kernel(const short* __restrict__ h,
                                                   const float* __restrict__ gW,
                                                   const float* __restrict__ gb,
                                                   float* __restrict__ g)
{
    int tid = blockIdx.x * 256 + threadIdx.x;
    int n = tid >> 6;
    if (n >= N_NODES) return;
    int lane = tid & 63;
    uint2 pk = *(const uint2*)(h + (size_t)n * H + lane * 4);
    float4 w = *(const float4*)(gW + lane * 4);
    float s = bf2f((unsigned short)(pk.x & 0xFFFF)) * w.x
            + bf2f((unsigned short)(pk.x >> 16))    * w.y
            + bf2f((unsigned short)(pk.y & 0xFFFF)) * w.z
            + bf2f((unsigned short)(pk.y >> 16))    * w.w;
    #pragma unroll
    for (int off = 32; off > 0; off >>= 1)
        s += __shfl_down(s, off);
    if (lane == 0) g[n] = s + gb[0];
}

// ---------------- per-graph softmax-gated readout ----------------
__global__ __launch_bounds__(256) void out_kernel(const short* __restrict__ h,
                                                  const float* __restrict__ g,
                                                  const int* __restrict__ sizes,
                                                  const float* __restrict__ outW,
                                                  const float* __restrict__ outB,
                                                  float* __restrict__ out)
{
    __shared__ float red[256];
    __shared__ float red4[4][256];
    int gid = blockIdx.x;
    int tid = threadIdx.x;
    int wave = tid >> 6;
    int lane = tid & 63;

    int start = 0, end = 0;
    {
        int c = 0;
        for (int i = 0; i < N_GRAPHS; i++) {
            int sz = sizes[i];
            if (i == gid) { start = c; end = c + sz; }
            c += sz;
        }
    }

    float m = -INFINITY;
    for (int n = start + tid; n < end; n += 256) m = fmaxf(m, g[n]);
    red[tid] = m; __syncthreads();
    for (int s = 128; s > 0; s >>= 1) {
        if (tid < s) red[tid] = fmaxf(red[tid], red[tid + s]);
        __syncthreads();
    }
    m = red[0]; __syncthreads();

    float s_ = 0.0f;
    for (int n = start + tid; n < end; n += 256) s_ += expf(g[n] - m);
    red[tid] = s_; __syncthreads();
    for (int s = 128; s > 0; s >>= 1) {
        if (tid < s) red[tid] += red[tid + s];
        __syncthreads();
    }
    float ssum = red[0]; __syncthreads();

    float a0 = 0.f, a1 = 0.f, a2 = 0.f, a3 = 0.f;
    for (int n = start + wave; n < end; n += 4) {
        float e = expf(g[n] - m);
        uint2 pk = *(const uint2*)(h + (size_t)n * H + lane * 4);
        a0 += e * bf2f((unsigned short)(pk.x & 0xFFFF));
        a1 += e * bf2f((unsigned short)(pk.x >> 16));
        a2 += e * bf2f((unsigned short)(pk.y & 0xFFFF));
        a3 += e * bf2f((unsigned short)(pk.y >> 16));
    }
    red4[wave][lane * 4 + 0] = a0;
    red4[wave][lane * 4 + 1] = a1;
    red4[wave][lane * 4 + 2] = a2;
    red4[wave][lane * 4 + 3] = a3;
    __syncthreads();
    float acc = red4[0][tid] + red4[1][tid] + red4[2][tid] + red4[3][tid];
    __syncthreads();

    float inv = 1.0f / (ssum + 1e-16f);
    for (int c = 0; c < 2; c++) {
        red[tid] = acc * outW[tid * 2 + c];
        __syncthreads();
        for (int s = 128; s > 0; s >>= 1) {
            if (tid < s) red[tid] += red[tid + s];
            __syncthreads();
        }
        if (tid == 0) out[gid * 2 + c] = red[0] * inv + outB[c] * (ssum * inv);
        __syncthreads();
    }
}

static inline size_t alup(size_t x) { return (x + 255) & ~(size_t)255; }

extern "C" void kernel_launch(void* const* d_in, const int* in_sizes, int n_in,
                              void* d_out, int out_size, void* d_ws, size_t ws_size,
                              hipStream_t stream)
{
    const int*   nodes  = (const int*)d_in[0];
    const int*   gsizes = (const int*)d_in[1];
    const int*   edges  = (const int*)d_in[2];
    const float* embed  = (const float*)d_in[3];
    const float* type_w = (const float*)d_in[4];
    const float* type_b = (const float*)d_in[5];
    const float* gru_W  = (const float*)d_in[6];
    const float* gru_U  = (const float*)d_in[7];
    const float* gru_bi = (const float*)d_in[8];
    const float* gru_br = (const float*)d_in[9];
    const float* gate_W = (const float*)d_in[10];
    const float* gate_b = (const float*)d_in[11];
    const float* out_W  = (const float*)d_in[12];
    const float* out_b  = (const float*)d_in[13];
    float* out = (float*)d_out;

    const int CHMAX = 33334;
    const int c0s[3] = {0, 33334, 66667};
    const int nrs[3] = {33334, 33333, 33333};

    // ---- workspace layout (bytes), total ~200 MB ----
    const size_t SZ_HB   = alup((size_t)N_NODES * H * 2);       // 51.2 MB x2
    const size_t SZ_SCR1 = alup((size_t)CHMAX * 1024 * 2);      // 68.3 MB (gath4 / S)
    const size_t SZ_SCR2 = alup((size_t)CHMAX * 256 * 2);       // 17.1 MB (msgs chunk)
    const size_t SZ_G    = alup((size_t)N_NODES * 4);
    const size_t SZ_PE   = alup((size_t)(L_POS + 1) * H * 4);   // 0.53 MB
    const size_t SZ_WST  = alup((size_t)2 * 256 * 1024 * 2);
    const size_t SZ_BC   = alup((size_t)2 * 1024 * 512 * 2);
    const size_t SZ_BIAS = alup((size_t)2 * 1024 * 4);
    const size_t SZ_CNT  = alup((size_t)NBUCK * 4);
    const size_t SZ_CUR  = SZ_CNT;
    const size_t SZ_OFF  = alup((size_t)(NBUCK + 1) * 4);
    const size_t SZ_SRC  = alup((size_t)N_EDGES * 4);
    const size_t SZ_PART = alup((size_t)NBLK * 4);
    size_t need = 2 * SZ_HB + SZ_SCR1 + SZ_SCR2 + SZ_G + SZ_PE + SZ_WST + SZ_BC + SZ_BIAS +
                  SZ_CNT + SZ_CUR + SZ_OFF + SZ_SRC + SZ_PART;
    if (ws_size < need) return;

    char* base = (char*)d_ws;
    short* hA     = (short*)base;  base += SZ_HB;
    short* hB     = (short*)base;  base += SZ_HB;
    short* scr1   = (short*)base;  base += SZ_SCR1;
    short* scr2   = (short*)base;  base += SZ_SCR2;
    float* g      = (float*)base;  base += SZ_G;
    float* peTab  = (float*)base;  base += SZ_PE;
    short* Wstack = (short*)base;  base += SZ_WST;
    short* Bcomb  = (short*)base;  base += SZ_BC;
    float* biasC  = (float*)base;  base += SZ_BIAS;
    int*   counts = (int*)base;    base += SZ_CNT;
    int*   cursors= (int*)base;    base += SZ_CUR;
    int*   offs   = (int*)base;    base += SZ_OFF;
    int*   srcs   = (int*)base;    base += SZ_SRC;
    int*   partial= (int*)base;    base += SZ_PART;

    // ---- prep ----
    pe_kernel<<<L_POS + 1, 256, 0, stream>>>(peTab);
    cvt_wstack<<<(2 * 256 * 1024) / 256, 256, 0, stream>>>(type_w, Wstack);
    cvt_comb<<<(2 * 1024 * 512) / 256, 256, 0, stream>>>(gru_W, gru_U, Bcomb);
    cvt_bias<<<8, 256, 0, stream>>>(gru_bi, gru_br, biasC);
    {
        int n4 = (int)((SZ_CNT + SZ_CUR) / 16);
        zero_int<<<(n4 + 255) / 256, 256, 0, stream>>>((int4*)counts, n4);
    }
    histo_kernel<<<(N_EDGES + 255) / 256, 256, 0, stream>>>(edges, counts);
    scan1<<<NBLK, 256, 0, stream>>>(counts, partial);
    scan2<<<1, 64, 0, stream>>>(partial, offs);
    scan3<<<NBLK, 256, 0, stream>>>(counts, partial, offs);
    fill_kernel<<<(N_EDGES + 255) / 256, 256, 0, stream>>>(edges, offs, cursors, srcs);
    init_h_kernel<<<N_NODES, H, 0, stream>>>(nodes, embed, peTab, hA);

    short* cur = hA;
    short* nxt = hB;
    const int steps[2] = {3, 1};
    for (int l = 0; l < 2; l++) {
        const short* WS = Wstack + (size_t)l * 256 * 1024;
        const float* Tb = type_b + (size_t)l * 4 * 256;
        const short* BC = Bcomb + (size_t)l * 1024 * 512;
        const float* Cb = biasC + (size_t)l * 1024;
        for (int s = 0; s < steps[l]; s++) {
            for (int c = 0; c < 3; c++) {
                int c0 = c0s[c], nr = nrs[c];
                int gb = (nr + 127) / 128;
                gather_kernel<<<(nr * 64 + 255) / 256, 256, 0, stream>>>(offs, srcs, cur, scr1, c0, nr);
                dim3 g1(gb, 2);
                mm_bf16<<<g1, 256, 0, stream>>>(scr1, 1024, nullptr, 0, 1024,
                                                WS, 1024, Tb, counts, c0,
                                                scr2, 256, nr);
                dim3 g2(gb, 8);
                mm_bf16<<<g2, 256, 0, stream>>>(scr2, 256, cur + (size_t)c0 * H, 256, 256,
                                                BC, 512, Cb, nullptr, 0,
                                                scr1, 1024, nr);
                gru_kernel<<<(nr * 64 + 255) / 256, 256, 0, stream>>>(cur, nxt, scr1, c0, nr);
            }
            short* t = cur; cur = nxt; nxt = t;
        }
    }

    gate_kernel<<<(N_NODES * 64) / 256, 256, 0, stream>>>(cur, gate_W, gate_b, g);
    out_kernel<<<N_GRAPHS, 256, 0, stream>>>(cur, g, gsizes, out_W, out_b, out);
}